// Round 1
// baseline (3075.213 us; speedup 1.0000x reference)
//
#include <hip/hip_runtime.h>
#include <math.h>

#define D_MODEL 1024
#define D_INNER 2048
#define D_STATE 16
#define D_CONV  4
#define DT_RANK 64
#define B_SZ    2
#define SEQ     2048
#define NTOK    (B_SZ*SEQ)          // 4096
#define DBL_N   (DT_RANK + 2*D_STATE) // 96

// ---------------- RMSNorm: one block per token ----------------
__global__ __launch_bounds__(256) void rmsnorm_kernel(
    const float* __restrict__ h, const float* __restrict__ w, float* __restrict__ out)
{
    int tok = blockIdx.x;
    const float4* row = (const float4*)(h + (size_t)tok * D_MODEL);
    float4 v = row[threadIdx.x];
    float ss = v.x*v.x + v.y*v.y + v.z*v.z + v.w*v.w;
    #pragma unroll
    for (int off = 32; off >= 1; off >>= 1) ss += __shfl_down(ss, off, 64);
    __shared__ float red[4];
    int wave = threadIdx.x >> 6, lane = threadIdx.x & 63;
    if (lane == 0) red[wave] = ss;
    __syncthreads();
    float tot = red[0] + red[1] + red[2] + red[3];
    float scale = rsqrtf(tot * (1.0f / D_MODEL) + 1e-5f);
    float4 wv = ((const float4*)w)[threadIdx.x];
    float4 o;
    o.x = v.x * scale * wv.x;
    o.y = v.y * scale * wv.y;
    o.z = v.z * scale * wv.z;
    o.w = v.w * scale * wv.w;
    ((float4*)(out + (size_t)tok * D_MODEL))[threadIdx.x] = o;
}

// ---------------- Generic fp32 GEMM: C = A @ W^T (+bias)(+act)(+add) ----------------
// A: M x K (row stride lda), W: N x K (row stride ldw), C: M x N (row stride ldc)
// act: 0 = none, 1 = softplus
__global__ __launch_bounds__(256) void gemm_kernel(
    const float* __restrict__ A, int lda,
    const float* __restrict__ W, int ldw,
    float* __restrict__ C, int ldc,
    int M, int N, int K,
    const float* __restrict__ bias,
    const float* __restrict__ add, int ldadd,
    int act)
{
    __shared__ float As[16][65];
    __shared__ float Ws[16][65];
    const int bm = blockIdx.y * 64;
    const int bn = blockIdx.x * 64;
    const int tid = threadIdx.x;
    const int tm = tid >> 4, tn = tid & 15;
    float acc[4][4] = {};
    for (int k0 = 0; k0 < K; k0 += 16) {
        #pragma unroll
        for (int j = 0; j < 4; ++j) {
            int e = tid + j * 256;
            int r = e >> 4, c = e & 15;
            As[c][r] = A[(size_t)(bm + r) * lda + k0 + c];
            int nr = bn + r;
            Ws[c][r] = (nr < N) ? W[(size_t)nr * ldw + k0 + c] : 0.0f;
        }
        __syncthreads();
        #pragma unroll
        for (int kk = 0; kk < 16; ++kk) {
            float a[4], wv[4];
            #pragma unroll
            for (int i = 0; i < 4; ++i) a[i] = As[kk][tm + 16 * i];
            #pragma unroll
            for (int j = 0; j < 4; ++j) wv[j] = Ws[kk][tn + 16 * j];
            #pragma unroll
            for (int i = 0; i < 4; ++i)
                #pragma unroll
                for (int j = 0; j < 4; ++j)
                    acc[i][j] = fmaf(a[i], wv[j], acc[i][j]);
        }
        __syncthreads();
    }
    #pragma unroll
    for (int i = 0; i < 4; ++i) {
        int row = bm + tm + 16 * i;
        #pragma unroll
        for (int j = 0; j < 4; ++j) {
            int col = bn + tn + 16 * j;
            if (col < N) {
                float v = acc[i][j];
                if (bias) v += bias[col];
                if (act == 1) v = (v > 20.0f) ? v : log1pf(__expf(v));
                if (add) v += add[(size_t)row * ldadd + col];
                C[(size_t)row * ldc + col] = v;
            }
        }
    }
}

// ---------------- Causal depthwise conv (k=4) + SiLU ----------------
// x lives in xz buffer (NTOK x 2*D_INNER), x = cols [0, D_INNER)
__global__ __launch_bounds__(256) void conv_silu_kernel(
    const float* __restrict__ xz, const float* __restrict__ cw,
    const float* __restrict__ cb, float* __restrict__ out)
{
    int idx = blockIdx.x * 256 + threadIdx.x;   // over NTOK*D_INNER
    int d = idx & (D_INNER - 1);
    int t = (idx >> 11) & (SEQ - 1);
    int b = idx >> 22;
    const float* xcol = xz + (size_t)b * SEQ * (2 * D_INNER) + d;
    float w0 = cw[d * 4 + 0], w1 = cw[d * 4 + 1], w2 = cw[d * 4 + 2], w3 = cw[d * 4 + 3];
    float acc = cb[d];
    if (t >= 3) acc = fmaf(xcol[(size_t)(t - 3) * (2 * D_INNER)], w0, acc);
    if (t >= 2) acc = fmaf(xcol[(size_t)(t - 2) * (2 * D_INNER)], w1, acc);
    if (t >= 1) acc = fmaf(xcol[(size_t)(t - 1) * (2 * D_INNER)], w2, acc);
    acc = fmaf(xcol[(size_t)t * (2 * D_INNER)], w3, acc);
    float sig = 1.0f / (1.0f + __expf(-acc));
    out[(size_t)(b * SEQ + t) * D_INNER + d] = acc * sig;
}

// ---------------- Selective scan: 16 lanes per (b,d) channel ----------------
__global__ __launch_bounds__(256) void scan_kernel(
    const float* __restrict__ dtb,   // NTOK x D_INNER
    const float* __restrict__ xconv, // NTOK x D_INNER
    const float* __restrict__ xz,    // NTOK x 2*D_INNER (z at +D_INNER)
    const float* __restrict__ dbl,   // NTOK x 96 (B at +64, C at +80)
    const float* __restrict__ A_log, // D_INNER x 16
    const float* __restrict__ Dvec,  // D_INNER
    float* __restrict__ y)           // NTOK x D_INNER
{
    int gid = blockIdx.x * 256 + threadIdx.x;
    int n = gid & 15;
    int g = gid >> 4;            // (b,d) group: 0..4095
    int d = g & (D_INNER - 1);
    int b = g >> 11;
    float A_n = -__expf(A_log[d * D_STATE + n]);
    float Dd = Dvec[d];
    const float* dt_base = dtb + (size_t)b * SEQ * D_INNER + d;
    const float* x_base  = xconv + (size_t)b * SEQ * D_INNER + d;
    const float* z_base  = xz + (size_t)b * SEQ * (2 * D_INNER) + D_INNER + d;
    const float* bc_base = dbl + (size_t)b * SEQ * DBL_N + DT_RANK + n;
    float* y_base = y + (size_t)b * SEQ * D_INNER + d;
    float h = 0.0f;
    for (int t = 0; t < SEQ; ++t) {
        float dt = dt_base[(size_t)t * D_INNER];
        float xv = x_base[(size_t)t * D_INNER];
        float Bn = bc_base[(size_t)t * DBL_N];
        float Cn = bc_base[(size_t)t * DBL_N + D_STATE];
        h = fmaf(h, __expf(dt * A_n), dt * xv * Bn);
        float p = h * Cn;
        p += __shfl_xor(p, 1, 16);
        p += __shfl_xor(p, 2, 16);
        p += __shfl_xor(p, 4, 16);
        p += __shfl_xor(p, 8, 16);
        if (n == 0) {
            float zv = z_base[(size_t)t * (2 * D_INNER)];
            float sig = 1.0f / (1.0f + __expf(-zv));
            y_base[(size_t)t * D_INNER] = (p + xv * Dd) * (zv * sig);
        }
    }
}

extern "C" void kernel_launch(void* const* d_in, const int* in_sizes, int n_in,
                              void* d_out, int out_size, void* d_ws, size_t ws_size,
                              hipStream_t stream) {
    const float* hs        = (const float*)d_in[0];   // (B,SEQ,D_MODEL)
    const float* norm_w    = (const float*)d_in[1];   // (D_MODEL)
    const float* in_proj_w = (const float*)d_in[2];   // (2*D_INNER, D_MODEL)
    const float* conv_w    = (const float*)d_in[3];   // (D_INNER,1,4)
    const float* conv_b    = (const float*)d_in[4];   // (D_INNER)
    const float* x_proj_w  = (const float*)d_in[5];   // (96, D_INNER)
    const float* dt_proj_w = (const float*)d_in[6];   // (D_INNER, DT_RANK)
    const float* dt_proj_b = (const float*)d_in[7];   // (D_INNER)
    const float* A_log     = (const float*)d_in[8];   // (D_INNER, D_STATE)
    const float* Dvec      = (const float*)d_in[9];   // (D_INNER)
    const float* out_proj_w= (const float*)d_in[10];  // (D_MODEL, D_INNER)
    float* out = (float*)d_out;

    float* wsf   = (float*)d_ws;
    float* hnorm = wsf;                                  // 4096x1024
    float* xz    = hnorm + (size_t)NTOK * D_MODEL;       // 4096x4096
    float* xconv = xz    + (size_t)NTOK * 2 * D_INNER;   // 4096x2048
    float* dbl   = xconv + (size_t)NTOK * D_INNER;       // 4096x96
    float* dtb   = dbl   + (size_t)NTOK * DBL_N;         // 4096x2048
    float* ybuf  = dtb   + (size_t)NTOK * D_INNER;       // 4096x2048

    // 1. RMSNorm
    rmsnorm_kernel<<<NTOK, 256, 0, stream>>>(hs, norm_w, hnorm);
    // 2. in_proj: xz = hnorm @ in_proj_w^T   (4096 x 4096, K=1024)
    gemm_kernel<<<dim3(64, 64), 256, 0, stream>>>(
        hnorm, D_MODEL, in_proj_w, D_MODEL, xz, 2 * D_INNER,
        NTOK, 2 * D_INNER, D_MODEL, nullptr, nullptr, 0, 0);
    // 3. depthwise causal conv + SiLU -> xconv
    conv_silu_kernel<<<(NTOK * D_INNER) / 256, 256, 0, stream>>>(xz, conv_w, conv_b, xconv);
    // 4. x_proj: dbl = xconv @ x_proj_w^T    (4096 x 96, K=2048)
    gemm_kernel<<<dim3(2, 64), 256, 0, stream>>>(
        xconv, D_INNER, x_proj_w, D_INNER, dbl, DBL_N,
        NTOK, DBL_N, D_INNER, nullptr, nullptr, 0, 0);
    // 5. dt_proj + bias + softplus: dtb = softplus(dbl[:, :64] @ dt_proj_w^T + b)
    gemm_kernel<<<dim3(32, 64), 256, 0, stream>>>(
        dbl, DBL_N, dt_proj_w, DT_RANK, dtb, D_INNER,
        NTOK, D_INNER, DT_RANK, dt_proj_b, nullptr, 0, 1);
    // 6. selective scan (+ x*D, * silu(z)) -> ybuf
    scan_kernel<<<(B_SZ * D_INNER * D_STATE) / 256, 256, 0, stream>>>(
        dtb, xconv, xz, dbl, A_log, Dvec, ybuf);
    // 7. out_proj + residual -> d_out
    gemm_kernel<<<dim3(16, 64), 256, 0, stream>>>(
        ybuf, D_INNER, out_proj_w, D_INNER, out, D_MODEL,
        NTOK, D_MODEL, D_INNER, nullptr, hs, D_MODEL, 0);
}

// Round 2
// 1886.622 us; speedup vs baseline: 1.6300x; 1.6300x over previous
//
#include <hip/hip_runtime.h>
#include <math.h>

#define D_MODEL 1024
#define D_INNER 2048
#define D_STATE 16
#define D_CONV  4
#define DT_RANK 64
#define B_SZ    2
#define SEQ     2048
#define NTOK    (B_SZ*SEQ)            // 4096
#define DBL_N   (DT_RANK + 2*D_STATE) // 96
#define CHUNK   128
#define NCHUNK  (SEQ/CHUNK)           // 16

// ---------------- RMSNorm: one block per token ----------------
__global__ __launch_bounds__(256) void rmsnorm_kernel(
    const float* __restrict__ h, const float* __restrict__ w, float* __restrict__ out)
{
    int tok = blockIdx.x;
    const float4* row = (const float4*)(h + (size_t)tok * D_MODEL);
    float4 v = row[threadIdx.x];
    float ss = v.x*v.x + v.y*v.y + v.z*v.z + v.w*v.w;
    #pragma unroll
    for (int off = 32; off >= 1; off >>= 1) ss += __shfl_down(ss, off, 64);
    __shared__ float red[4];
    int wave = threadIdx.x >> 6, lane = threadIdx.x & 63;
    if (lane == 0) red[wave] = ss;
    __syncthreads();
    float tot = red[0] + red[1] + red[2] + red[3];
    float scale = rsqrtf(tot * (1.0f / D_MODEL) + 1e-5f);
    float4 wv = ((const float4*)w)[threadIdx.x];
    float4 o;
    o.x = v.x * scale * wv.x;
    o.y = v.y * scale * wv.y;
    o.z = v.z * scale * wv.z;
    o.w = v.w * scale * wv.w;
    ((float4*)(out + (size_t)tok * D_MODEL))[threadIdx.x] = o;
}

// ---------------- Generic fp32 GEMM: C = A @ W^T (+bias)(+act)(+add) ----------------
__global__ __launch_bounds__(256) void gemm_kernel(
    const float* __restrict__ A, int lda,
    const float* __restrict__ W, int ldw,
    float* __restrict__ C, int ldc,
    int M, int N, int K,
    const float* __restrict__ bias,
    const float* __restrict__ add, int ldadd,
    int act)
{
    __shared__ float As[16][65];
    __shared__ float Ws[16][65];
    const int bm = blockIdx.y * 64;
    const int bn = blockIdx.x * 64;
    const int tid = threadIdx.x;
    const int tm = tid >> 4, tn = tid & 15;
    float acc[4][4] = {};
    for (int k0 = 0; k0 < K; k0 += 16) {
        #pragma unroll
        for (int j = 0; j < 4; ++j) {
            int e = tid + j * 256;
            int r = e >> 4, c = e & 15;
            As[c][r] = A[(size_t)(bm + r) * lda + k0 + c];
            int nr = bn + r;
            Ws[c][r] = (nr < N) ? W[(size_t)nr * ldw + k0 + c] : 0.0f;
        }
        __syncthreads();
        #pragma unroll
        for (int kk = 0; kk < 16; ++kk) {
            float a[4], wv[4];
            #pragma unroll
            for (int i = 0; i < 4; ++i) a[i] = As[kk][tm + 16 * i];
            #pragma unroll
            for (int j = 0; j < 4; ++j) wv[j] = Ws[kk][tn + 16 * j];
            #pragma unroll
            for (int i = 0; i < 4; ++i)
                #pragma unroll
                for (int j = 0; j < 4; ++j)
                    acc[i][j] = fmaf(a[i], wv[j], acc[i][j]);
        }
        __syncthreads();
    }
    #pragma unroll
    for (int i = 0; i < 4; ++i) {
        int row = bm + tm + 16 * i;
        #pragma unroll
        for (int j = 0; j < 4; ++j) {
            int col = bn + tn + 16 * j;
            if (col < N) {
                float v = acc[i][j];
                if (bias) v += bias[col];
                if (act == 1) v = (v > 20.0f) ? v : log1pf(__expf(v));
                if (add) v += add[(size_t)row * ldadd + col];
                C[(size_t)row * ldc + col] = v;
            }
        }
    }
}

// ---------------- Causal depthwise conv (k=4) + SiLU ----------------
__global__ __launch_bounds__(256) void conv_silu_kernel(
    const float* __restrict__ xz, const float* __restrict__ cw,
    const float* __restrict__ cb, float* __restrict__ out)
{
    int idx = blockIdx.x * 256 + threadIdx.x;   // over NTOK*D_INNER
    int d = idx & (D_INNER - 1);
    int t = (idx >> 11) & (SEQ - 1);
    int b = idx >> 22;
    const float* xcol = xz + (size_t)b * SEQ * (2 * D_INNER) + d;
    float w0 = cw[d * 4 + 0], w1 = cw[d * 4 + 1], w2 = cw[d * 4 + 2], w3 = cw[d * 4 + 3];
    float acc = cb[d];
    if (t >= 3) acc = fmaf(xcol[(size_t)(t - 3) * (2 * D_INNER)], w0, acc);
    if (t >= 2) acc = fmaf(xcol[(size_t)(t - 2) * (2 * D_INNER)], w1, acc);
    if (t >= 1) acc = fmaf(xcol[(size_t)(t - 1) * (2 * D_INNER)], w2, acc);
    acc = fmaf(xcol[(size_t)t * (2 * D_INNER)], w3, acc);
    float sig = 1.0f / (1.0f + __expf(-acc));
    out[(size_t)(b * SEQ + t) * D_INNER + d] = acc * sig;
}

// ---------------- Chunk-parallel selective scan ----------------
// One block per (b,d). tid = chunk*16 + n.  Linear recurrence h_t = a_t h + b_t:
//   phase 1: per-chunk (a_prod, h_part) with h_init=0
//   phase 2: 16-chunk prefix scan in LDS -> h_init per chunk
//   phase 3: re-scan chunk with true h_init, emit y = (sum_n h*C + x*D) * silu(z)
__global__ __launch_bounds__(256) void scan_chunked_kernel(
    const float* __restrict__ dtb,   // NTOK x D_INNER
    const float* __restrict__ xconv, // NTOK x D_INNER
    const float* __restrict__ xz,    // NTOK x 2*D_INNER (z at +D_INNER)
    const float* __restrict__ dbl,   // NTOK x 96 (B at +64, C at +80)
    const float* __restrict__ A_log, // D_INNER x 16
    const float* __restrict__ Dvec,  // D_INNER
    float* __restrict__ y)           // NTOK x D_INNER
{
    const int d = blockIdx.x & (D_INNER - 1);
    const int b = blockIdx.x >> 11;
    const int n = threadIdx.x & 15;
    const int c = threadIdx.x >> 4;           // chunk 0..15
    const int t0 = c * CHUNK;

    const float A_n = -__expf(A_log[d * D_STATE + n]);
    const float Dd = Dvec[d];
    const float* dt_base = dtb   + (size_t)b * SEQ * D_INNER + d;
    const float* x_base  = xconv + (size_t)b * SEQ * D_INNER + d;
    const float* z_base  = xz    + (size_t)b * SEQ * (2 * D_INNER) + D_INNER + d;
    const float* bc_base = dbl   + (size_t)b * SEQ * DBL_N + DT_RANK + n;
    float* y_base = y + (size_t)b * SEQ * D_INNER + d;

    // ---- phase 1: chunk summary with h_init = 0 ----
    float h = 0.0f, sumdt = 0.0f;
    for (int t = t0; t < t0 + CHUNK; ++t) {
        float dt = dt_base[(size_t)t * D_INNER];
        float xv = x_base[(size_t)t * D_INNER];
        float Bn = bc_base[(size_t)t * DBL_N];
        sumdt += dt;
        h = fmaf(h, __expf(dt * A_n), dt * xv * Bn);
    }
    float aprod = __expf(A_n * sumdt);

    // ---- phase 2: inter-chunk prefix scan (16 entries per n) ----
    __shared__ float s_ap[NCHUNK][D_STATE];
    __shared__ float s_hp[NCHUNK][D_STATE];
    __shared__ float s_hi[NCHUNK][D_STATE];
    s_ap[c][n] = aprod;
    s_hp[c][n] = h;
    __syncthreads();
    if (c == 0) {           // 16 threads (one per n) do the serial 16-chunk scan
        float hh = 0.0f;
        #pragma unroll
        for (int cc = 0; cc < NCHUNK; ++cc) {
            s_hi[cc][n] = hh;
            hh = fmaf(hh, s_ap[cc][n], s_hp[cc][n]);
        }
    }
    __syncthreads();
    h = s_hi[c][n];

    // ---- phase 3: re-scan with true h_init, emit y ----
    for (int t = t0; t < t0 + CHUNK; ++t) {
        float dt = dt_base[(size_t)t * D_INNER];
        float xv = x_base[(size_t)t * D_INNER];
        float Bn = bc_base[(size_t)t * DBL_N];
        float Cn = bc_base[(size_t)t * DBL_N + D_STATE];
        h = fmaf(h, __expf(dt * A_n), dt * xv * Bn);
        float p = h * Cn;
        p += __shfl_xor(p, 1, 16);
        p += __shfl_xor(p, 2, 16);
        p += __shfl_xor(p, 4, 16);
        p += __shfl_xor(p, 8, 16);
        if (n == 0) {
            float zv = z_base[(size_t)t * (2 * D_INNER)];
            float sig = 1.0f / (1.0f + __expf(-zv));
            y_base[(size_t)t * D_INNER] = (p + xv * Dd) * (zv * sig);
        }
    }
}

extern "C" void kernel_launch(void* const* d_in, const int* in_sizes, int n_in,
                              void* d_out, int out_size, void* d_ws, size_t ws_size,
                              hipStream_t stream) {
    const float* hs        = (const float*)d_in[0];   // (B,SEQ,D_MODEL)
    const float* norm_w    = (const float*)d_in[1];   // (D_MODEL)
    const float* in_proj_w = (const float*)d_in[2];   // (2*D_INNER, D_MODEL)
    const float* conv_w    = (const float*)d_in[3];   // (D_INNER,1,4)
    const float* conv_b    = (const float*)d_in[4];   // (D_INNER)
    const float* x_proj_w  = (const float*)d_in[5];   // (96, D_INNER)
    const float* dt_proj_w = (const float*)d_in[6];   // (D_INNER, DT_RANK)
    const float* dt_proj_b = (const float*)d_in[7];   // (D_INNER)
    const float* A_log     = (const float*)d_in[8];   // (D_INNER, D_STATE)
    const float* Dvec      = (const float*)d_in[9];   // (D_INNER)
    const float* out_proj_w= (const float*)d_in[10];  // (D_MODEL, D_INNER)
    float* out = (float*)d_out;

    float* wsf   = (float*)d_ws;
    float* hnorm = wsf;                                  // 4096x1024
    float* xz    = hnorm + (size_t)NTOK * D_MODEL;       // 4096x4096
    float* xconv = xz    + (size_t)NTOK * 2 * D_INNER;   // 4096x2048
    float* dbl   = xconv + (size_t)NTOK * D_INNER;       // 4096x96
    float* dtb   = dbl   + (size_t)NTOK * DBL_N;         // 4096x2048
    float* ybuf  = dtb   + (size_t)NTOK * D_INNER;       // 4096x2048

    // 1. RMSNorm
    rmsnorm_kernel<<<NTOK, 256, 0, stream>>>(hs, norm_w, hnorm);
    // 2. in_proj: xz = hnorm @ in_proj_w^T   (4096 x 4096, K=1024)
    gemm_kernel<<<dim3(64, 64), 256, 0, stream>>>(
        hnorm, D_MODEL, in_proj_w, D_MODEL, xz, 2 * D_INNER,
        NTOK, 2 * D_INNER, D_MODEL, nullptr, nullptr, 0, 0);
    // 3. depthwise causal conv + SiLU -> xconv
    conv_silu_kernel<<<(NTOK * D_INNER) / 256, 256, 0, stream>>>(xz, conv_w, conv_b, xconv);
    // 4. x_proj: dbl = xconv @ x_proj_w^T    (4096 x 96, K=2048)
    gemm_kernel<<<dim3(2, 64), 256, 0, stream>>>(
        xconv, D_INNER, x_proj_w, D_INNER, dbl, DBL_N,
        NTOK, DBL_N, D_INNER, nullptr, nullptr, 0, 0);
    // 5. dt_proj + bias + softplus
    gemm_kernel<<<dim3(32, 64), 256, 0, stream>>>(
        dbl, DBL_N, dt_proj_w, DT_RANK, dtb, D_INNER,
        NTOK, D_INNER, DT_RANK, dt_proj_b, nullptr, 0, 1);
    // 6. chunk-parallel selective scan (+ x*D, * silu(z)) -> ybuf
    scan_chunked_kernel<<<B_SZ * D_INNER, 256, 0, stream>>>(
        dtb, xconv, xz, dbl, A_log, Dvec, ybuf);
    // 7. out_proj + residual -> d_out
    gemm_kernel<<<dim3(16, 64), 256, 0, stream>>>(
        ybuf, D_INNER, out_proj_w, D_INNER, out, D_MODEL,
        NTOK, D_MODEL, D_INNER, nullptr, hs, D_MODEL, 0);
}

// Round 3
// 990.854 us; speedup vs baseline: 3.1036x; 1.9040x over previous
//
#include <hip/hip_runtime.h>
#include <math.h>

#define D_MODEL 1024
#define D_INNER 2048
#define D_STATE 16
#define D_CONV  4
#define DT_RANK 64
#define B_SZ    2
#define SEQ     2048
#define NTOK    (B_SZ*SEQ)            // 4096
#define DBL_N   (DT_RANK + 2*D_STATE) // 96
#define CHUNK   128
#define NCHUNK  (SEQ/CHUNK)           // 16

typedef __attribute__((ext_vector_type(8))) short short8;
typedef __attribute__((ext_vector_type(4))) float f32x4;

__device__ __forceinline__ unsigned short f2bf(float f) {
    union { float f; unsigned int u; } v; v.f = f;
    unsigned int r = v.u + 0x7fff + ((v.u >> 16) & 1);   // RNE
    return (unsigned short)(r >> 16);
}

// ---------------- RMSNorm: one block per token, bf16 output ----------------
__global__ __launch_bounds__(256) void rmsnorm_kernel(
    const float* __restrict__ h, const float* __restrict__ w, unsigned short* __restrict__ out)
{
    int tok = blockIdx.x;
    const float4* row = (const float4*)(h + (size_t)tok * D_MODEL);
    float4 v = row[threadIdx.x];
    float ss = v.x*v.x + v.y*v.y + v.z*v.z + v.w*v.w;
    #pragma unroll
    for (int off = 32; off >= 1; off >>= 1) ss += __shfl_down(ss, off, 64);
    __shared__ float red[4];
    int wave = threadIdx.x >> 6, lane = threadIdx.x & 63;
    if (lane == 0) red[wave] = ss;
    __syncthreads();
    float tot = red[0] + red[1] + red[2] + red[3];
    float scale = rsqrtf(tot * (1.0f / D_MODEL) + 1e-5f);
    float4 wv = ((const float4*)w)[threadIdx.x];
    ushort4 o;
    o.x = f2bf(v.x * scale * wv.x);
    o.y = f2bf(v.y * scale * wv.y);
    o.z = f2bf(v.z * scale * wv.z);
    o.w = f2bf(v.w * scale * wv.w);
    ((ushort4*)(out + (size_t)tok * D_MODEL))[threadIdx.x] = o;
}

// ---------------- fp32 -> bf16 cast (for weights) ----------------
__global__ __launch_bounds__(256) void cast_bf16_kernel(
    const float4* __restrict__ in, ushort4* __restrict__ out, int n4)
{
    int i = blockIdx.x * 256 + threadIdx.x;
    if (i < n4) {
        float4 v = in[i];
        ushort4 o; o.x = f2bf(v.x); o.y = f2bf(v.y); o.z = f2bf(v.z); o.w = f2bf(v.w);
        out[i] = o;
    }
}

// ---------------- bf16 MFMA GEMM: C(fp32) = A @ W^T (+add) ----------------
// A: M x lda bf16 (row-major), W: N x ldw bf16 (row-major), C: M x ldc fp32
// 128x128 tile, BK=32, 256 threads = 4 waves (2x2 of 64x64), 16x16x32 MFMA.
__global__ __launch_bounds__(256) void mfma_gemm_kernel(
    const unsigned short* __restrict__ A, int lda,
    const unsigned short* __restrict__ W, int ldw,
    float* __restrict__ C, int ldc,
    int K,
    const float* __restrict__ add, int ldadd)
{
    __shared__ __align__(16) unsigned short As[128 * 32];   // 8 KB
    __shared__ __align__(16) unsigned short Bs[128 * 32];   // 8 KB
    const int bm = blockIdx.y * 128;
    const int bn = blockIdx.x * 128;
    const int tid = threadIdx.x;
    const int lane = tid & 63;
    const int wave = tid >> 6;
    const int wm = (wave >> 1) * 64;
    const int wn = (wave & 1) * 64;
    const int frow = lane & 15;      // fragment row (m or n)
    const int quad = lane >> 4;      // k-slice selector

    f32x4 acc[4][4];
    #pragma unroll
    for (int i = 0; i < 4; ++i)
        #pragma unroll
        for (int j = 0; j < 4; ++j)
            acc[i][j] = (f32x4){0.f, 0.f, 0.f, 0.f};

    for (int k0 = 0; k0 < K; k0 += 32) {
        __syncthreads();   // protect LDS from previous iteration's readers
        // stage A-tile and B-tile: 8192 B each, 16 B per lane per issue.
        // issue unit: 64 lanes x 16B = 1024 B = 16 rows of 64 B.
        #pragma unroll
        for (int i = 0; i < 2; ++i) {
            int q = (wave * 2 + i) * 64 + lane;     // chunk index 0..511
            int r = q >> 2, cc = q & 3;
            const unsigned short* ga = A + (size_t)(bm + r) * lda + k0 + cc * 8;
            const unsigned short* gb = W + (size_t)(bn + r) * ldw + k0 + cc * 8;
            __builtin_amdgcn_global_load_lds(
                (const __attribute__((address_space(1))) void*)ga,
                (__attribute__((address_space(3))) void*)(As + (wave * 2 + i) * 512),
                16, 0, 0);
            __builtin_amdgcn_global_load_lds(
                (const __attribute__((address_space(1))) void*)gb,
                (__attribute__((address_space(3))) void*)(Bs + (wave * 2 + i) * 512),
                16, 0, 0);
        }
        __syncthreads();   // drains vmcnt before barrier (compiler-inserted)
        short8 af[4], bf[4];
        #pragma unroll
        for (int i = 0; i < 4; ++i)
            af[i] = *(const short8*)&As[(wm + i * 16 + frow) * 32 + quad * 8];
        #pragma unroll
        for (int j = 0; j < 4; ++j)
            bf[j] = *(const short8*)&Bs[(wn + j * 16 + frow) * 32 + quad * 8];
        #pragma unroll
        for (int i = 0; i < 4; ++i)
            #pragma unroll
            for (int j = 0; j < 4; ++j)
                acc[i][j] = __builtin_amdgcn_mfma_f32_16x16x32_bf16(
                    af[i], bf[j], acc[i][j], 0, 0, 0);
    }

    // epilogue: C/D layout col=lane&15, row=quad*4+reg
    #pragma unroll
    for (int i = 0; i < 4; ++i) {
        #pragma unroll
        for (int r = 0; r < 4; ++r) {
            int row = bm + wm + i * 16 + quad * 4 + r;
            #pragma unroll
            for (int j = 0; j < 4; ++j) {
                int col = bn + wn + j * 16 + frow;
                float v = acc[i][j][r];
                if (add) v += add[(size_t)row * ldadd + col];
                C[(size_t)row * ldc + col] = v;
            }
        }
    }
}

// ---------------- Generic fp32 GEMM (small GEMMs): C = A @ W^T (+bias)(+act) ----------------
__global__ __launch_bounds__(256) void gemm_kernel(
    const float* __restrict__ A, int lda,
    const float* __restrict__ W, int ldw,
    float* __restrict__ C, int ldc,
    int M, int N, int K,
    const float* __restrict__ bias,
    int act)
{
    __shared__ float As[16][65];
    __shared__ float Ws[16][65];
    const int bm = blockIdx.y * 64;
    const int bn = blockIdx.x * 64;
    const int tid = threadIdx.x;
    const int tm = tid >> 4, tn = tid & 15;
    float acc[4][4] = {};
    for (int k0 = 0; k0 < K; k0 += 16) {
        #pragma unroll
        for (int j = 0; j < 4; ++j) {
            int e = tid + j * 256;
            int r = e >> 4, c = e & 15;
            As[c][r] = A[(size_t)(bm + r) * lda + k0 + c];
            int nr = bn + r;
            Ws[c][r] = (nr < N) ? W[(size_t)nr * ldw + k0 + c] : 0.0f;
        }
        __syncthreads();
        #pragma unroll
        for (int kk = 0; kk < 16; ++kk) {
            float a[4], wv[4];
            #pragma unroll
            for (int i = 0; i < 4; ++i) a[i] = As[kk][tm + 16 * i];
            #pragma unroll
            for (int j = 0; j < 4; ++j) wv[j] = Ws[kk][tn + 16 * j];
            #pragma unroll
            for (int i = 0; i < 4; ++i)
                #pragma unroll
                for (int j = 0; j < 4; ++j)
                    acc[i][j] = fmaf(a[i], wv[j], acc[i][j]);
        }
        __syncthreads();
    }
    #pragma unroll
    for (int i = 0; i < 4; ++i) {
        int row = bm + tm + 16 * i;
        #pragma unroll
        for (int j = 0; j < 4; ++j) {
            int col = bn + tn + 16 * j;
            if (col < N) {
                float v = acc[i][j];
                if (bias) v += bias[col];
                if (act == 1) v = (v > 20.0f) ? v : log1pf(__expf(v));
                C[(size_t)row * ldc + col] = v;
            }
        }
    }
}

// ---------------- Causal depthwise conv (k=4) + SiLU ----------------
__global__ __launch_bounds__(256) void conv_silu_kernel(
    const float* __restrict__ xz, const float* __restrict__ cw,
    const float* __restrict__ cb, float* __restrict__ out)
{
    int idx = blockIdx.x * 256 + threadIdx.x;   // over NTOK*D_INNER
    int d = idx & (D_INNER - 1);
    int t = (idx >> 11) & (SEQ - 1);
    int b = idx >> 22;
    const float* xcol = xz + (size_t)b * SEQ * (2 * D_INNER) + d;
    float w0 = cw[d * 4 + 0], w1 = cw[d * 4 + 1], w2 = cw[d * 4 + 2], w3 = cw[d * 4 + 3];
    float acc = cb[d];
    if (t >= 3) acc = fmaf(xcol[(size_t)(t - 3) * (2 * D_INNER)], w0, acc);
    if (t >= 2) acc = fmaf(xcol[(size_t)(t - 2) * (2 * D_INNER)], w1, acc);
    if (t >= 1) acc = fmaf(xcol[(size_t)(t - 1) * (2 * D_INNER)], w2, acc);
    acc = fmaf(xcol[(size_t)t * (2 * D_INNER)], w3, acc);
    float sig = 1.0f / (1.0f + __expf(-acc));
    out[(size_t)(b * SEQ + t) * D_INNER + d] = acc * sig;
}

// ---------------- Chunk-parallel selective scan, bf16 y output ----------------
__global__ __launch_bounds__(256) void scan_chunked_kernel(
    const float* __restrict__ dtb,   // NTOK x D_INNER
    const float* __restrict__ xconv, // NTOK x D_INNER
    const float* __restrict__ xz,    // NTOK x 2*D_INNER (z at +D_INNER)
    const float* __restrict__ dbl,   // NTOK x 96 (B at +64, C at +80)
    const float* __restrict__ A_log, // D_INNER x 16
    const float* __restrict__ Dvec,  // D_INNER
    unsigned short* __restrict__ y)  // NTOK x D_INNER (bf16)
{
    const int d = blockIdx.x & (D_INNER - 1);
    const int b = blockIdx.x >> 11;
    const int n = threadIdx.x & 15;
    const int c = threadIdx.x >> 4;           // chunk 0..15
    const int t0 = c * CHUNK;

    const float A_n = -__expf(A_log[d * D_STATE + n]);
    const float Dd = Dvec[d];
    const float* dt_base = dtb   + (size_t)b * SEQ * D_INNER + d;
    const float* x_base  = xconv + (size_t)b * SEQ * D_INNER + d;
    const float* z_base  = xz    + (size_t)b * SEQ * (2 * D_INNER) + D_INNER + d;
    const float* bc_base = dbl   + (size_t)b * SEQ * DBL_N + DT_RANK + n;
    unsigned short* y_base = y + (size_t)b * SEQ * D_INNER + d;

    // ---- phase 1: chunk summary with h_init = 0 ----
    float h = 0.0f, sumdt = 0.0f;
    for (int t = t0; t < t0 + CHUNK; ++t) {
        float dt = dt_base[(size_t)t * D_INNER];
        float xv = x_base[(size_t)t * D_INNER];
        float Bn = bc_base[(size_t)t * DBL_N];
        sumdt += dt;
        h = fmaf(h, __expf(dt * A_n), dt * xv * Bn);
    }
    float aprod = __expf(A_n * sumdt);

    // ---- phase 2: inter-chunk prefix scan ----
    __shared__ float s_ap[NCHUNK][D_STATE];
    __shared__ float s_hp[NCHUNK][D_STATE];
    __shared__ float s_hi[NCHUNK][D_STATE];
    s_ap[c][n] = aprod;
    s_hp[c][n] = h;
    __syncthreads();
    if (c == 0) {
        float hh = 0.0f;
        #pragma unroll
        for (int cc = 0; cc < NCHUNK; ++cc) {
            s_hi[cc][n] = hh;
            hh = fmaf(hh, s_ap[cc][n], s_hp[cc][n]);
        }
    }
    __syncthreads();
    h = s_hi[c][n];

    // ---- phase 3: re-scan with true h_init, emit y ----
    for (int t = t0; t < t0 + CHUNK; ++t) {
        float dt = dt_base[(size_t)t * D_INNER];
        float xv = x_base[(size_t)t * D_INNER];
        float Bn = bc_base[(size_t)t * DBL_N];
        float Cn = bc_base[(size_t)t * DBL_N + D_STATE];
        h = fmaf(h, __expf(dt * A_n), dt * xv * Bn);
        float p = h * Cn;
        p += __shfl_xor(p, 1, 16);
        p += __shfl_xor(p, 2, 16);
        p += __shfl_xor(p, 4, 16);
        p += __shfl_xor(p, 8, 16);
        if (n == 0) {
            float zv = z_base[(size_t)t * (2 * D_INNER)];
            float sig = 1.0f / (1.0f + __expf(-zv));
            y_base[(size_t)t * D_INNER] = f2bf((p + xv * Dd) * (zv * sig));
        }
    }
}

extern "C" void kernel_launch(void* const* d_in, const int* in_sizes, int n_in,
                              void* d_out, int out_size, void* d_ws, size_t ws_size,
                              hipStream_t stream) {
    const float* hs        = (const float*)d_in[0];
    const float* norm_w    = (const float*)d_in[1];
    const float* in_proj_w = (const float*)d_in[2];
    const float* conv_w    = (const float*)d_in[3];
    const float* conv_b    = (const float*)d_in[4];
    const float* x_proj_w  = (const float*)d_in[5];
    const float* dt_proj_w = (const float*)d_in[6];
    const float* dt_proj_b = (const float*)d_in[7];
    const float* A_log     = (const float*)d_in[8];
    const float* Dvec      = (const float*)d_in[9];
    const float* out_proj_w= (const float*)d_in[10];
    float* out = (float*)d_out;

    float* wsf   = (float*)d_ws;
    float* xz    = wsf;                                  // 4096x4096 fp32
    float* xconv = xz    + (size_t)NTOK * 2 * D_INNER;   // 4096x2048 fp32
    float* dbl   = xconv + (size_t)NTOK * D_INNER;       // 4096x96   fp32
    float* dtb   = dbl   + (size_t)NTOK * DBL_N;         // 4096x2048 fp32
    unsigned short* hnorm_bf = (unsigned short*)(dtb + (size_t)NTOK * D_INNER); // 4096x1024
    unsigned short* ybuf_bf  = hnorm_bf + (size_t)NTOK * D_MODEL;               // 4096x2048
    unsigned short* wi_bf    = ybuf_bf + (size_t)NTOK * D_INNER;                // 4096x1024
    unsigned short* wo_bf    = wi_bf + (size_t)(2 * D_INNER) * D_MODEL;         // 1024x2048

    // weight casts (independent of data path)
    cast_bf16_kernel<<<(2 * D_INNER * D_MODEL / 4 + 255) / 256, 256, 0, stream>>>(
        (const float4*)in_proj_w, (ushort4*)wi_bf, 2 * D_INNER * D_MODEL / 4);
    cast_bf16_kernel<<<(D_MODEL * D_INNER / 4 + 255) / 256, 256, 0, stream>>>(
        (const float4*)out_proj_w, (ushort4*)wo_bf, D_MODEL * D_INNER / 4);

    // 1. RMSNorm -> bf16
    rmsnorm_kernel<<<NTOK, 256, 0, stream>>>(hs, norm_w, hnorm_bf);
    // 2. in_proj (MFMA): xz = hnorm @ in_proj_w^T   (4096 x 4096, K=1024)
    mfma_gemm_kernel<<<dim3((2 * D_INNER) / 128, NTOK / 128), 256, 0, stream>>>(
        hnorm_bf, D_MODEL, wi_bf, D_MODEL, xz, 2 * D_INNER, D_MODEL, nullptr, 0);
    // 3. depthwise causal conv + SiLU -> xconv
    conv_silu_kernel<<<(NTOK * D_INNER) / 256, 256, 0, stream>>>(xz, conv_w, conv_b, xconv);
    // 4. x_proj: dbl = xconv @ x_proj_w^T    (4096 x 96, K=2048)
    gemm_kernel<<<dim3(2, 64), 256, 0, stream>>>(
        xconv, D_INNER, x_proj_w, D_INNER, dbl, DBL_N,
        NTOK, DBL_N, D_INNER, nullptr, 0);
    // 5. dt_proj + bias + softplus
    gemm_kernel<<<dim3(32, 64), 256, 0, stream>>>(
        dbl, DBL_N, dt_proj_w, DT_RANK, dtb, D_INNER,
        NTOK, D_INNER, DT_RANK, dt_proj_b, 1);
    // 6. chunk-parallel selective scan -> ybuf (bf16)
    scan_chunked_kernel<<<B_SZ * D_INNER, 256, 0, stream>>>(
        dtb, xconv, xz, dbl, A_log, Dvec, ybuf_bf);
    // 7. out_proj (MFMA) + residual -> d_out
    mfma_gemm_kernel<<<dim3(D_MODEL / 128, NTOK / 128), 256, 0, stream>>>(
        ybuf_bf, D_INNER, wo_bf, D_INNER, out, D_MODEL, D_INNER, hs, D_MODEL);
}

// Round 4
// 631.503 us; speedup vs baseline: 4.8697x; 1.5690x over previous
//
#include <hip/hip_runtime.h>
#include <math.h>

#define D_MODEL 1024
#define D_INNER 2048
#define D_STATE 16
#define D_CONV  4
#define DT_RANK 64
#define B_SZ    2
#define SEQ     2048
#define NTOK    (B_SZ*SEQ)            // 4096
#define DBL_N   (DT_RANK + 2*D_STATE) // 96
#define CHUNK   128
#define NCHUNK  (SEQ/CHUNK)           // 16

typedef __attribute__((ext_vector_type(8))) short short8;
typedef __attribute__((ext_vector_type(4))) float f32x4;

__device__ __forceinline__ unsigned short f2bf(float f) {
    union { float f; unsigned int u; } v; v.f = f;
    unsigned int r = v.u + 0x7fff + ((v.u >> 16) & 1);   // RNE
    return (unsigned short)(r >> 16);
}

// ---------------- RMSNorm: one block per token, bf16 output ----------------
__global__ __launch_bounds__(256) void rmsnorm_kernel(
    const float* __restrict__ h, const float* __restrict__ w, unsigned short* __restrict__ out)
{
    int tok = blockIdx.x;
    const float4* row = (const float4*)(h + (size_t)tok * D_MODEL);
    float4 v = row[threadIdx.x];
    float ss = v.x*v.x + v.y*v.y + v.z*v.z + v.w*v.w;
    #pragma unroll
    for (int off = 32; off >= 1; off >>= 1) ss += __shfl_down(ss, off, 64);
    __shared__ float red[4];
    int wave = threadIdx.x >> 6, lane = threadIdx.x & 63;
    if (lane == 0) red[wave] = ss;
    __syncthreads();
    float tot = red[0] + red[1] + red[2] + red[3];
    float scale = rsqrtf(tot * (1.0f / D_MODEL) + 1e-5f);
    float4 wv = ((const float4*)w)[threadIdx.x];
    ushort4 o;
    o.x = f2bf(v.x * scale * wv.x);
    o.y = f2bf(v.y * scale * wv.y);
    o.z = f2bf(v.z * scale * wv.z);
    o.w = f2bf(v.w * scale * wv.w);
    ((ushort4*)(out + (size_t)tok * D_MODEL))[threadIdx.x] = o;
}

// ---------------- fp32 -> bf16 cast ----------------
__global__ __launch_bounds__(256) void cast_bf16_kernel(
    const float4* __restrict__ in, ushort4* __restrict__ out, int n4)
{
    int i = blockIdx.x * 256 + threadIdx.x;
    if (i < n4) {
        float4 v = in[i];
        ushort4 o; o.x = f2bf(v.x); o.y = f2bf(v.y); o.z = f2bf(v.z); o.w = f2bf(v.w);
        out[i] = o;
    }
}

// ---------------- bf16 MFMA GEMM: C(fp32) = A @ W^T (+add), N-guarded ----------------
__global__ __launch_bounds__(256) void mfma_gemm_kernel(
    const unsigned short* __restrict__ A, int lda,
    const unsigned short* __restrict__ W, int ldw,
    float* __restrict__ C, int ldc,
    int K, int Nmax,
    const float* __restrict__ add, int ldadd)
{
    __shared__ __align__(16) unsigned short As[128 * 32];
    __shared__ __align__(16) unsigned short Bs[128 * 32];
    const int bm = blockIdx.y * 128;
    const int bn = blockIdx.x * 128;
    const int tid = threadIdx.x;
    const int lane = tid & 63;
    const int wave = tid >> 6;
    const int wm = (wave >> 1) * 64;
    const int wn = (wave & 1) * 64;
    const int frow = lane & 15;
    const int quad = lane >> 4;

    f32x4 acc[4][4];
    #pragma unroll
    for (int i = 0; i < 4; ++i)
        #pragma unroll
        for (int j = 0; j < 4; ++j)
            acc[i][j] = (f32x4){0.f, 0.f, 0.f, 0.f};

    for (int k0 = 0; k0 < K; k0 += 32) {
        __syncthreads();
        #pragma unroll
        for (int i = 0; i < 2; ++i) {
            int q = (wave * 2 + i) * 64 + lane;
            int r = q >> 2, cc = q & 3;
            const unsigned short* ga = A + (size_t)(bm + r) * lda + k0 + cc * 8;
            const unsigned short* gb = W + (size_t)(bn + r) * ldw + k0 + cc * 8;
            __builtin_amdgcn_global_load_lds(
                (const __attribute__((address_space(1))) void*)ga,
                (__attribute__((address_space(3))) void*)(As + (wave * 2 + i) * 512),
                16, 0, 0);
            __builtin_amdgcn_global_load_lds(
                (const __attribute__((address_space(1))) void*)gb,
                (__attribute__((address_space(3))) void*)(Bs + (wave * 2 + i) * 512),
                16, 0, 0);
        }
        __syncthreads();
        short8 af[4], bf[4];
        #pragma unroll
        for (int i = 0; i < 4; ++i)
            af[i] = *(const short8*)&As[(wm + i * 16 + frow) * 32 + quad * 8];
        #pragma unroll
        for (int j = 0; j < 4; ++j)
            bf[j] = *(const short8*)&Bs[(wn + j * 16 + frow) * 32 + quad * 8];
        #pragma unroll
        for (int i = 0; i < 4; ++i)
            #pragma unroll
            for (int j = 0; j < 4; ++j)
                acc[i][j] = __builtin_amdgcn_mfma_f32_16x16x32_bf16(
                    af[i], bf[j], acc[i][j], 0, 0, 0);
    }

    // epilogue: C/D layout col=lane&15, row=quad*4+reg
    #pragma unroll
    for (int i = 0; i < 4; ++i) {
        #pragma unroll
        for (int r = 0; r < 4; ++r) {
            int row = bm + wm + i * 16 + quad * 4 + r;
            #pragma unroll
            for (int j = 0; j < 4; ++j) {
                int col = bn + wn + j * 16 + frow;
                if (col < Nmax) {
                    float v = acc[i][j][r];
                    if (add) v += add[(size_t)row * ldadd + col];
                    C[(size_t)row * ldc + col] = v;
                }
            }
        }
    }
}

// ---------------- Generic fp32 GEMM: C = A @ W^T (+bias)(+act) ----------------
__global__ __launch_bounds__(256) void gemm_kernel(
    const float* __restrict__ A, int lda,
    const float* __restrict__ W, int ldw,
    float* __restrict__ C, int ldc,
    int M, int N, int K,
    const float* __restrict__ bias,
    int act)
{
    __shared__ float As[16][65];
    __shared__ float Ws[16][65];
    const int bm = blockIdx.y * 64;
    const int bn = blockIdx.x * 64;
    const int tid = threadIdx.x;
    const int tm = tid >> 4, tn = tid & 15;
    float acc[4][4] = {};
    for (int k0 = 0; k0 < K; k0 += 16) {
        #pragma unroll
        for (int j = 0; j < 4; ++j) {
            int e = tid + j * 256;
            int r = e >> 4, c = e & 15;
            As[c][r] = A[(size_t)(bm + r) * lda + k0 + c];
            int nr = bn + r;
            Ws[c][r] = (nr < N) ? W[(size_t)nr * ldw + k0 + c] : 0.0f;
        }
        __syncthreads();
        #pragma unroll
        for (int kk = 0; kk < 16; ++kk) {
            float a[4], wv[4];
            #pragma unroll
            for (int i = 0; i < 4; ++i) a[i] = As[kk][tm + 16 * i];
            #pragma unroll
            for (int j = 0; j < 4; ++j) wv[j] = Ws[kk][tn + 16 * j];
            #pragma unroll
            for (int i = 0; i < 4; ++i)
                #pragma unroll
                for (int j = 0; j < 4; ++j)
                    acc[i][j] = fmaf(a[i], wv[j], acc[i][j]);
        }
        __syncthreads();
    }
    #pragma unroll
    for (int i = 0; i < 4; ++i) {
        int row = bm + tm + 16 * i;
        #pragma unroll
        for (int j = 0; j < 4; ++j) {
            int col = bn + tn + 16 * j;
            if (col < N) {
                float v = acc[i][j];
                if (bias) v += bias[col];
                if (act == 1) v = (v > 20.0f) ? v : log1pf(__expf(v));
                C[(size_t)row * ldc + col] = v;
            }
        }
    }
}

// ---------------- Causal depthwise conv (k=4) + SiLU (fp32 + optional bf16 out) ----------------
__global__ __launch_bounds__(256) void conv_silu_kernel(
    const float* __restrict__ xz, const float* __restrict__ cw,
    const float* __restrict__ cb, float* __restrict__ out,
    unsigned short* __restrict__ out_bf)
{
    int idx = blockIdx.x * 256 + threadIdx.x;   // over NTOK*D_INNER
    int d = idx & (D_INNER - 1);
    int t = (idx >> 11) & (SEQ - 1);
    int b = idx >> 22;
    const float* xcol = xz + (size_t)b * SEQ * (2 * D_INNER) + d;
    float w0 = cw[d * 4 + 0], w1 = cw[d * 4 + 1], w2 = cw[d * 4 + 2], w3 = cw[d * 4 + 3];
    float acc = cb[d];
    if (t >= 3) acc = fmaf(xcol[(size_t)(t - 3) * (2 * D_INNER)], w0, acc);
    if (t >= 2) acc = fmaf(xcol[(size_t)(t - 2) * (2 * D_INNER)], w1, acc);
    if (t >= 1) acc = fmaf(xcol[(size_t)(t - 1) * (2 * D_INNER)], w2, acc);
    acc = fmaf(xcol[(size_t)t * (2 * D_INNER)], w3, acc);
    float sig = 1.0f / (1.0f + __expf(-acc));
    float r = acc * sig;
    size_t o = (size_t)(b * SEQ + t) * D_INNER + d;
    out[o] = r;
    if (out_bf) out_bf[o] = f2bf(r);
}

// ---------------- Scan phase 1: per-chunk summaries ----------------
// block = 16 d x 16 n; grid = (NCHUNK, D_INNER/16, B_SZ)
__global__ __launch_bounds__(256) void scan_phase1_kernel(
    const float* __restrict__ dtb, const float* __restrict__ xconv,
    const float* __restrict__ dbl, const float* __restrict__ A_log,
    float* __restrict__ sum_a, float* __restrict__ sum_h)
{
    const int n = threadIdx.x & 15;
    const int d = blockIdx.y * 16 + (threadIdx.x >> 4);
    const int c = blockIdx.x;
    const int b = blockIdx.z;
    const int t0 = c * CHUNK;
    const float A_n = -__expf(A_log[d * D_STATE + n]);
    const float* dt_p = dtb   + ((size_t)b * SEQ + t0) * D_INNER + d;
    const float* x_p  = xconv + ((size_t)b * SEQ + t0) * D_INNER + d;
    const float* B_p  = dbl   + ((size_t)b * SEQ + t0) * DBL_N + DT_RANK + n;
    float h = 0.f, sumdt = 0.f;
    #pragma unroll 4
    for (int t = 0; t < CHUNK; ++t) {
        float dt = dt_p[(size_t)t * D_INNER];
        float xv = x_p[(size_t)t * D_INNER];
        float Bn = B_p[(size_t)t * DBL_N];
        sumdt += dt;
        h = fmaf(h, __expf(dt * A_n), dt * xv * Bn);
    }
    size_t base = (((size_t)b * D_INNER + d) * D_STATE + n) * NCHUNK + c;
    sum_a[base] = __expf(A_n * sumdt);
    sum_h[base] = h;
}

// ---------------- Scan phase 2: inter-chunk carry (in-place over sum_h) ----------------
__global__ __launch_bounds__(256) void scan_carry_kernel(
    const float* __restrict__ sum_a, float* __restrict__ sum_h)
{
    size_t g = (size_t)blockIdx.x * 256 + threadIdx.x;   // 65536 (b,d,n) groups
    size_t base = g * NCHUNK;
    float a[NCHUNK], h[NCHUNK];
    #pragma unroll
    for (int i = 0; i < NCHUNK; ++i) { a[i] = sum_a[base + i]; h[i] = sum_h[base + i]; }
    float hh = 0.f;
    #pragma unroll
    for (int cc = 0; cc < NCHUNK; ++cc) {
        float nx = fmaf(hh, a[cc], h[cc]);
        h[cc] = hh;          // h_init for chunk cc
        hh = nx;
    }
    #pragma unroll
    for (int i = 0; i < NCHUNK; ++i) sum_h[base + i] = h[i];
}

// ---------------- Scan phase 3: re-scan with carry, emit y ----------------
__global__ __launch_bounds__(256) void scan_phase3_kernel(
    const float* __restrict__ dtb, const float* __restrict__ xconv,
    const float* __restrict__ xz, const float* __restrict__ dbl,
    const float* __restrict__ A_log, const float* __restrict__ Dvec,
    const float* __restrict__ hinit, unsigned short* __restrict__ y)
{
    const int n = threadIdx.x & 15;
    const int d = blockIdx.y * 16 + (threadIdx.x >> 4);
    const int c = blockIdx.x;
    const int b = blockIdx.z;
    const int t0 = c * CHUNK;
    const float A_n = -__expf(A_log[d * D_STATE + n]);
    const float Dd = Dvec[d];
    const float* dt_p = dtb   + ((size_t)b * SEQ + t0) * D_INNER + d;
    const float* x_p  = xconv + ((size_t)b * SEQ + t0) * D_INNER + d;
    const float* z_p  = xz    + ((size_t)b * SEQ + t0) * (2 * D_INNER) + D_INNER + d;
    const float* B_p  = dbl   + ((size_t)b * SEQ + t0) * DBL_N + DT_RANK + n;
    unsigned short* y_p = y + ((size_t)b * SEQ + t0) * D_INNER + d;
    float h = hinit[(((size_t)b * D_INNER + d) * D_STATE + n) * NCHUNK + c];
    #pragma unroll 2
    for (int t = 0; t < CHUNK; ++t) {
        float dt = dt_p[(size_t)t * D_INNER];
        float xv = x_p[(size_t)t * D_INNER];
        float Bn = B_p[(size_t)t * DBL_N];
        float Cn = B_p[(size_t)t * DBL_N + D_STATE];
        h = fmaf(h, __expf(dt * A_n), dt * xv * Bn);
        float p = h * Cn;
        p += __shfl_xor(p, 1, 16);
        p += __shfl_xor(p, 2, 16);
        p += __shfl_xor(p, 4, 16);
        p += __shfl_xor(p, 8, 16);
        if (n == 0) {
            float zv = z_p[(size_t)t * (2 * D_INNER)];
            float sig = 1.0f / (1.0f + __expf(-zv));
            y_p[(size_t)t * D_INNER] = f2bf((p + xv * Dd) * (zv * sig));
        }
    }
}

extern "C" void kernel_launch(void* const* d_in, const int* in_sizes, int n_in,
                              void* d_out, int out_size, void* d_ws, size_t ws_size,
                              hipStream_t stream) {
    const float* hs        = (const float*)d_in[0];
    const float* norm_w    = (const float*)d_in[1];
    const float* in_proj_w = (const float*)d_in[2];
    const float* conv_w    = (const float*)d_in[3];
    const float* conv_b    = (const float*)d_in[4];
    const float* x_proj_w  = (const float*)d_in[5];
    const float* dt_proj_w = (const float*)d_in[6];
    const float* dt_proj_b = (const float*)d_in[7];
    const float* A_log     = (const float*)d_in[8];
    const float* Dvec      = (const float*)d_in[9];
    const float* out_proj_w= (const float*)d_in[10];
    float* out = (float*)d_out;

    float* wsf   = (float*)d_ws;
    float* xz    = wsf;                                   // 16,777,216 f
    float* xconv = xz    + (size_t)16777216;              //  8,388,608 f
    float* dbl   = xconv + (size_t)8388608;               //    393,216 f
    float* dtb   = dbl   + (size_t)393216;                //  8,388,608 f
    float* sum_a = dtb   + (size_t)8388608;               //  1,048,576 f
    float* sum_h = sum_a + (size_t)1048576;               //  1,048,576 f
    unsigned short* hnorm_bf = (unsigned short*)(sum_h + 1048576); // 4,194,304 us
    unsigned short* ybuf_bf  = hnorm_bf + (size_t)4194304;         // 8,388,608 us
    unsigned short* wi_bf    = ybuf_bf + (size_t)8388608;          // 4,194,304 us
    unsigned short* wo_bf    = wi_bf + (size_t)4194304;            // 2,097,152 us
    unsigned short* xconv_bf = wo_bf + (size_t)2097152;            // 8,388,608 us (opt)
    unsigned short* wx_bf    = xconv_bf + (size_t)8388608;         //   262,144 us (opt)
    const size_t full_bytes = ((size_t)36044800) * 4 + ((size_t)18874368 + 8650752) * 2;
    const bool mfma_xproj = ws_size >= full_bytes;

    // weight casts
    cast_bf16_kernel<<<(2 * D_INNER * D_MODEL / 4 + 255) / 256, 256, 0, stream>>>(
        (const float4*)in_proj_w, (ushort4*)wi_bf, 2 * D_INNER * D_MODEL / 4);
    cast_bf16_kernel<<<(D_MODEL * D_INNER / 4 + 255) / 256, 256, 0, stream>>>(
        (const float4*)out_proj_w, (ushort4*)wo_bf, D_MODEL * D_INNER / 4);
    if (mfma_xproj)
        cast_bf16_kernel<<<(DBL_N * D_INNER / 4 + 255) / 256, 256, 0, stream>>>(
            (const float4*)x_proj_w, (ushort4*)wx_bf, DBL_N * D_INNER / 4);

    // 1. RMSNorm -> bf16
    rmsnorm_kernel<<<NTOK, 256, 0, stream>>>(hs, norm_w, hnorm_bf);
    // 2. in_proj (MFMA): xz = hnorm @ in_proj_w^T
    mfma_gemm_kernel<<<dim3((2 * D_INNER) / 128, NTOK / 128), 256, 0, stream>>>(
        hnorm_bf, D_MODEL, wi_bf, D_MODEL, xz, 2 * D_INNER, D_MODEL, 2 * D_INNER, nullptr, 0);
    // 3. depthwise causal conv + SiLU -> xconv (+bf16 copy)
    conv_silu_kernel<<<(NTOK * D_INNER) / 256, 256, 0, stream>>>(
        xz, conv_w, conv_b, xconv, mfma_xproj ? xconv_bf : nullptr);
    // 4. x_proj: dbl = xconv @ x_proj_w^T (N=96)
    if (mfma_xproj) {
        mfma_gemm_kernel<<<dim3(1, NTOK / 128), 256, 0, stream>>>(
            xconv_bf, D_INNER, wx_bf, D_INNER, dbl, DBL_N, D_INNER, DBL_N, nullptr, 0);
    } else {
        gemm_kernel<<<dim3(2, 64), 256, 0, stream>>>(
            xconv, D_INNER, x_proj_w, D_INNER, dbl, DBL_N,
            NTOK, DBL_N, D_INNER, nullptr, 0);
    }
    // 5. dt_proj + bias + softplus
    gemm_kernel<<<dim3(32, 64), 256, 0, stream>>>(
        dbl, DBL_N, dt_proj_w, DT_RANK, dtb, D_INNER,
        NTOK, D_INNER, DT_RANK, dt_proj_b, 1);
    // 6. scan: phase1 -> carry -> phase3
    scan_phase1_kernel<<<dim3(NCHUNK, D_INNER / 16, B_SZ), 256, 0, stream>>>(
        dtb, xconv, dbl, A_log, sum_a, sum_h);
    scan_carry_kernel<<<(B_SZ * D_INNER * D_STATE) / 256, 256, 0, stream>>>(sum_a, sum_h);
    scan_phase3_kernel<<<dim3(NCHUNK, D_INNER / 16, B_SZ), 256, 0, stream>>>(
        dtb, xconv, xz, dbl, A_log, Dvec, sum_h, ybuf_bf);
    // 7. out_proj (MFMA) + residual -> d_out
    mfma_gemm_kernel<<<dim3(D_MODEL / 128, NTOK / 128), 256, 0, stream>>>(
        ybuf_bf, D_INNER, wo_bf, D_INNER, out, D_MODEL, D_INNER, D_MODEL, hs, D_MODEL);
}

// Round 5
// 422.054 us; speedup vs baseline: 7.2863x; 1.4963x over previous
//
#include <hip/hip_runtime.h>
#include <math.h>

#define D_MODEL 1024
#define D_INNER 2048
#define D_STATE 16
#define D_CONV  4
#define DT_RANK 64
#define B_SZ    2
#define SEQ     2048
#define NTOK    (B_SZ*SEQ)            // 4096
#define DBL_N   (DT_RANK + 2*D_STATE) // 96
#define CHUNK   64
#define NCHUNK  (SEQ/CHUNK)           // 32

typedef __attribute__((ext_vector_type(8))) short short8;
typedef __attribute__((ext_vector_type(4))) float f32x4;

__device__ __forceinline__ unsigned short f2bf(float f) {
    union { float f; unsigned int u; } v; v.f = f;
    unsigned int r = v.u + 0x7fff + ((v.u >> 16) & 1);   // RNE
    return (unsigned short)(r >> 16);
}
__device__ __forceinline__ float bf2f(unsigned short u) {
    union { unsigned int u; float f; } v; v.u = ((unsigned int)u) << 16;
    return v.f;
}

// ---------------- RMSNorm: one block per token, bf16 output ----------------
__global__ __launch_bounds__(256) void rmsnorm_kernel(
    const float* __restrict__ h, const float* __restrict__ w, unsigned short* __restrict__ out)
{
    int tok = blockIdx.x;
    const float4* row = (const float4*)(h + (size_t)tok * D_MODEL);
    float4 v = row[threadIdx.x];
    float ss = v.x*v.x + v.y*v.y + v.z*v.z + v.w*v.w;
    #pragma unroll
    for (int off = 32; off >= 1; off >>= 1) ss += __shfl_down(ss, off, 64);
    __shared__ float red[4];
    int wave = threadIdx.x >> 6, lane = threadIdx.x & 63;
    if (lane == 0) red[wave] = ss;
    __syncthreads();
    float tot = red[0] + red[1] + red[2] + red[3];
    float scale = rsqrtf(tot * (1.0f / D_MODEL) + 1e-5f);
    float4 wv = ((const float4*)w)[threadIdx.x];
    ushort4 o;
    o.x = f2bf(v.x * scale * wv.x);
    o.y = f2bf(v.y * scale * wv.y);
    o.z = f2bf(v.z * scale * wv.z);
    o.w = f2bf(v.w * scale * wv.w);
    ((ushort4*)(out + (size_t)tok * D_MODEL))[threadIdx.x] = o;
}

// ---------------- fp32 -> bf16 cast ----------------
__global__ __launch_bounds__(256) void cast_bf16_kernel(
    const float4* __restrict__ in, ushort4* __restrict__ out, int n4)
{
    int i = blockIdx.x * 256 + threadIdx.x;
    if (i < n4) {
        float4 v = in[i];
        ushort4 o; o.x = f2bf(v.x); o.y = f2bf(v.y); o.z = f2bf(v.z); o.w = f2bf(v.w);
        out[i] = o;
    }
}

// ---------------- bf16 MFMA GEMM: C(fp32) = A @ W^T (+add), N-guarded ----------------
__global__ __launch_bounds__(256) void mfma_gemm_kernel(
    const unsigned short* __restrict__ A, int lda,
    const unsigned short* __restrict__ W, int ldw,
    float* __restrict__ C, int ldc,
    int K, int Nmax,
    const float* __restrict__ add, int ldadd)
{
    __shared__ __align__(16) unsigned short As[128 * 32];
    __shared__ __align__(16) unsigned short Bs[128 * 32];
    const int bm = blockIdx.y * 128;
    const int bn = blockIdx.x * 128;
    const int tid = threadIdx.x;
    const int lane = tid & 63;
    const int wave = tid >> 6;
    const int wm = (wave >> 1) * 64;
    const int wn = (wave & 1) * 64;
    const int frow = lane & 15;
    const int quad = lane >> 4;

    f32x4 acc[4][4];
    #pragma unroll
    for (int i = 0; i < 4; ++i)
        #pragma unroll
        for (int j = 0; j < 4; ++j)
            acc[i][j] = (f32x4){0.f, 0.f, 0.f, 0.f};

    for (int k0 = 0; k0 < K; k0 += 32) {
        __syncthreads();
        #pragma unroll
        for (int i = 0; i < 2; ++i) {
            int q = (wave * 2 + i) * 64 + lane;
            int r = q >> 2, cc = q & 3;
            const unsigned short* ga = A + (size_t)(bm + r) * lda + k0 + cc * 8;
            const unsigned short* gb = W + (size_t)(bn + r) * ldw + k0 + cc * 8;
            __builtin_amdgcn_global_load_lds(
                (const __attribute__((address_space(1))) void*)ga,
                (__attribute__((address_space(3))) void*)(As + (wave * 2 + i) * 512),
                16, 0, 0);
            __builtin_amdgcn_global_load_lds(
                (const __attribute__((address_space(1))) void*)gb,
                (__attribute__((address_space(3))) void*)(Bs + (wave * 2 + i) * 512),
                16, 0, 0);
        }
        __syncthreads();
        short8 af[4], bf[4];
        #pragma unroll
        for (int i = 0; i < 4; ++i)
            af[i] = *(const short8*)&As[(wm + i * 16 + frow) * 32 + quad * 8];
        #pragma unroll
        for (int j = 0; j < 4; ++j)
            bf[j] = *(const short8*)&Bs[(wn + j * 16 + frow) * 32 + quad * 8];
        #pragma unroll
        for (int i = 0; i < 4; ++i)
            #pragma unroll
            for (int j = 0; j < 4; ++j)
                acc[i][j] = __builtin_amdgcn_mfma_f32_16x16x32_bf16(
                    af[i], bf[j], acc[i][j], 0, 0, 0);
    }

    // epilogue: C/D layout col=lane&15, row=quad*4+reg
    #pragma unroll
    for (int i = 0; i < 4; ++i) {
        #pragma unroll
        for (int r = 0; r < 4; ++r) {
            int row = bm + wm + i * 16 + quad * 4 + r;
            #pragma unroll
            for (int j = 0; j < 4; ++j) {
                int col = bn + wn + j * 16 + frow;
                if (col < Nmax) {
                    float v = acc[i][j][r];
                    if (add) v += add[(size_t)row * ldadd + col];
                    C[(size_t)row * ldc + col] = v;
                }
            }
        }
    }
}

// ---------------- Generic fp32 GEMM (dt_proj): C = A @ W^T (+bias)(+act) ----------------
__global__ __launch_bounds__(256) void gemm_kernel(
    const float* __restrict__ A, int lda,
    const float* __restrict__ W, int ldw,
    float* __restrict__ C, int ldc,
    int M, int N, int K,
    const float* __restrict__ bias,
    int act)
{
    __shared__ float As[16][65];
    __shared__ float Ws[16][65];
    const int bm = blockIdx.y * 64;
    const int bn = blockIdx.x * 64;
    const int tid = threadIdx.x;
    const int tm = tid >> 4, tn = tid & 15;
    float acc[4][4] = {};
    for (int k0 = 0; k0 < K; k0 += 16) {
        #pragma unroll
        for (int j = 0; j < 4; ++j) {
            int e = tid + j * 256;
            int r = e >> 4, c = e & 15;
            As[c][r] = A[(size_t)(bm + r) * lda + k0 + c];
            int nr = bn + r;
            Ws[c][r] = (nr < N) ? W[(size_t)nr * ldw + k0 + c] : 0.0f;
        }
        __syncthreads();
        #pragma unroll
        for (int kk = 0; kk < 16; ++kk) {
            float a[4], wv[4];
            #pragma unroll
            for (int i = 0; i < 4; ++i) a[i] = As[kk][tm + 16 * i];
            #pragma unroll
            for (int j = 0; j < 4; ++j) wv[j] = Ws[kk][tn + 16 * j];
            #pragma unroll
            for (int i = 0; i < 4; ++i)
                #pragma unroll
                for (int j = 0; j < 4; ++j)
                    acc[i][j] = fmaf(a[i], wv[j], acc[i][j]);
        }
        __syncthreads();
    }
    #pragma unroll
    for (int i = 0; i < 4; ++i) {
        int row = bm + tm + 16 * i;
        #pragma unroll
        for (int j = 0; j < 4; ++j) {
            int col = bn + tn + 16 * j;
            if (col < N) {
                float v = acc[i][j];
                if (bias) v += bias[col];
                if (act == 1) v = (v > 20.0f) ? v : log1pf(__expf(v));
                C[(size_t)row * ldc + col] = v;
            }
        }
    }
}

// ---------------- Causal depthwise conv (k=4) + SiLU -> bf16 ----------------
__global__ __launch_bounds__(256) void conv_silu_kernel(
    const float* __restrict__ xz, const float* __restrict__ cw,
    const float* __restrict__ cb, unsigned short* __restrict__ out_bf)
{
    int idx = blockIdx.x * 256 + threadIdx.x;   // over NTOK*D_INNER
    int d = idx & (D_INNER - 1);
    int t = (idx >> 11) & (SEQ - 1);
    int b = idx >> 22;
    const float* xcol = xz + (size_t)b * SEQ * (2 * D_INNER) + d;
    float w0 = cw[d * 4 + 0], w1 = cw[d * 4 + 1], w2 = cw[d * 4 + 2], w3 = cw[d * 4 + 3];
    float acc = cb[d];
    if (t >= 3) acc = fmaf(xcol[(size_t)(t - 3) * (2 * D_INNER)], w0, acc);
    if (t >= 2) acc = fmaf(xcol[(size_t)(t - 2) * (2 * D_INNER)], w1, acc);
    if (t >= 1) acc = fmaf(xcol[(size_t)(t - 1) * (2 * D_INNER)], w2, acc);
    acc = fmaf(xcol[(size_t)t * (2 * D_INNER)], w3, acc);
    float sig = 1.0f / (1.0f + __expf(-acc));
    out_bf[(size_t)(b * SEQ + t) * D_INNER + d] = f2bf(acc * sig);
}

// ---------------- Scan phase 1: per-chunk summaries, one thread per d ----------------
// grid = (NCHUNK, D_INNER/256, B_SZ), block = 256 (one d per thread)
__global__ __launch_bounds__(256) void scan_phase1_kernel(
    const float* __restrict__ dtb, const unsigned short* __restrict__ xconv,
    const float* __restrict__ dbl, const float* __restrict__ A_log,
    float* __restrict__ sum_a, float* __restrict__ sum_h)
{
    const int d = blockIdx.y * 256 + threadIdx.x;
    const int c = blockIdx.x;
    const int b = blockIdx.z;
    const int t0 = c * CHUNK;

    float An[D_STATE];
    bool fast = true;
    #pragma unroll
    for (int n = 0; n < D_STATE; ++n) {
        An[n] = -__expf(A_log[d * D_STATE + n]);
        fast = fast && (fabsf(An[n] + (float)(n + 1)) < 2e-3f);
    }
    const float* dt_p = dtb + ((size_t)b * SEQ + t0) * D_INNER + d;
    const unsigned short* x_p = xconv + ((size_t)b * SEQ + t0) * D_INNER + d;
    const float* Brow = dbl + ((size_t)b * SEQ + t0) * DBL_N + DT_RANK;   // wave-uniform

    float h[D_STATE];
    #pragma unroll
    for (int n = 0; n < D_STATE; ++n) h[n] = 0.f;
    float sumdt = 0.f;

    if (fast) {
        for (int t = 0; t < CHUNK; ++t) {
            float dt = dt_p[(size_t)t * D_INNER];
            float xv = bf2f(x_p[(size_t)t * D_INNER]);
            const float4* B4 = (const float4*)(Brow + (size_t)t * DBL_N);
            float4 b0 = B4[0], b1 = B4[1], b2 = B4[2], b3 = B4[3];
            float Bv[16] = {b0.x,b0.y,b0.z,b0.w, b1.x,b1.y,b1.z,b1.w,
                            b2.x,b2.y,b2.z,b2.w, b3.x,b3.y,b3.z,b3.w};
            sumdt += dt;
            float e1 = __expf(-dt);
            float dtx = dt * xv;
            float ea = 1.f;
            #pragma unroll
            for (int n = 0; n < D_STATE; ++n) {
                ea *= e1;                                  // ea = exp(-dt)^(n+1) = exp(dt*A_n)
                h[n] = fmaf(h[n], ea, dtx * Bv[n]);
            }
        }
    } else {
        for (int t = 0; t < CHUNK; ++t) {
            float dt = dt_p[(size_t)t * D_INNER];
            float xv = bf2f(x_p[(size_t)t * D_INNER]);
            const float4* B4 = (const float4*)(Brow + (size_t)t * DBL_N);
            float4 b0 = B4[0], b1 = B4[1], b2 = B4[2], b3 = B4[3];
            float Bv[16] = {b0.x,b0.y,b0.z,b0.w, b1.x,b1.y,b1.z,b1.w,
                            b2.x,b2.y,b2.z,b2.w, b3.x,b3.y,b3.z,b3.w};
            sumdt += dt;
            float dtx = dt * xv;
            #pragma unroll
            for (int n = 0; n < D_STATE; ++n) {
                float ea = __expf(dt * An[n]);
                h[n] = fmaf(h[n], ea, dtx * Bv[n]);
            }
        }
    }

    float a[D_STATE];
    if (fast) {
        float E = __expf(-sumdt);
        float ea = 1.f;
        #pragma unroll
        for (int n = 0; n < D_STATE; ++n) { ea *= E; a[n] = ea; }
    } else {
        #pragma unroll
        for (int n = 0; n < D_STATE; ++n) a[n] = __expf(An[n] * sumdt);
    }
    size_t base = (((size_t)b * D_INNER + d) * NCHUNK + c) * D_STATE;
    #pragma unroll
    for (int i = 0; i < 4; ++i) {
        ((float4*)(sum_a + base))[i] = (float4){a[4*i], a[4*i+1], a[4*i+2], a[4*i+3]};
        ((float4*)(sum_h + base))[i] = (float4){h[4*i], h[4*i+1], h[4*i+2], h[4*i+3]};
    }
}

// ---------------- Scan phase 2: inter-chunk carry (in-place over sum_h) ----------------
__global__ __launch_bounds__(256) void scan_carry_kernel(
    const float* __restrict__ sum_a, float* __restrict__ sum_h)
{
    size_t g = (size_t)blockIdx.x * 256 + threadIdx.x;   // (b,d,n): 65536 groups
    size_t bd = g >> 4;
    int n = (int)(g & 15);
    size_t base = bd * NCHUNK * D_STATE + n;
    float hh = 0.f;
    for (int c = 0; c < NCHUNK; ++c) {
        size_t idx = base + (size_t)c * D_STATE;
        float a = sum_a[idx];
        float hp = sum_h[idx];
        sum_h[idx] = hh;          // h_init for chunk c
        hh = fmaf(hh, a, hp);
    }
}

// ---------------- Scan phase 3: re-scan with carry, emit y (bf16) ----------------
__global__ __launch_bounds__(256) void scan_phase3_kernel(
    const float* __restrict__ dtb, const unsigned short* __restrict__ xconv,
    const float* __restrict__ xz, const float* __restrict__ dbl,
    const float* __restrict__ A_log, const float* __restrict__ Dvec,
    const float* __restrict__ hinit, unsigned short* __restrict__ y)
{
    const int d = blockIdx.y * 256 + threadIdx.x;
    const int c = blockIdx.x;
    const int b = blockIdx.z;
    const int t0 = c * CHUNK;

    float An[D_STATE];
    bool fast = true;
    #pragma unroll
    for (int n = 0; n < D_STATE; ++n) {
        An[n] = -__expf(A_log[d * D_STATE + n]);
        fast = fast && (fabsf(An[n] + (float)(n + 1)) < 2e-3f);
    }
    const float Dd = Dvec[d];
    const float* dt_p = dtb + ((size_t)b * SEQ + t0) * D_INNER + d;
    const unsigned short* x_p = xconv + ((size_t)b * SEQ + t0) * D_INNER + d;
    const float* z_p = xz + ((size_t)b * SEQ + t0) * (2 * D_INNER) + D_INNER + d;
    const float* Brow = dbl + ((size_t)b * SEQ + t0) * DBL_N + DT_RANK;
    unsigned short* y_p = y + ((size_t)b * SEQ + t0) * D_INNER + d;

    size_t base = (((size_t)b * D_INNER + d) * NCHUNK + c) * D_STATE;
    float h[D_STATE];
    #pragma unroll
    for (int i = 0; i < 4; ++i) {
        float4 hv = ((const float4*)(hinit + base))[i];
        h[4*i] = hv.x; h[4*i+1] = hv.y; h[4*i+2] = hv.z; h[4*i+3] = hv.w;
    }

    if (fast) {
        for (int t = 0; t < CHUNK; ++t) {
            float dt = dt_p[(size_t)t * D_INNER];
            float xv = bf2f(x_p[(size_t)t * D_INNER]);
            const float4* B4 = (const float4*)(Brow + (size_t)t * DBL_N);
            float4 b0 = B4[0], b1 = B4[1], b2 = B4[2], b3 = B4[3];
            float4 c0 = B4[4], c1 = B4[5], c2 = B4[6], c3 = B4[7];
            float Bv[16] = {b0.x,b0.y,b0.z,b0.w, b1.x,b1.y,b1.z,b1.w,
                            b2.x,b2.y,b2.z,b2.w, b3.x,b3.y,b3.z,b3.w};
            float Cv[16] = {c0.x,c0.y,c0.z,c0.w, c1.x,c1.y,c1.z,c1.w,
                            c2.x,c2.y,c2.z,c2.w, c3.x,c3.y,c3.z,c3.w};
            float e1 = __expf(-dt);
            float dtx = dt * xv;
            float ea = 1.f, yy = 0.f;
            #pragma unroll
            for (int n = 0; n < D_STATE; ++n) {
                ea *= e1;
                h[n] = fmaf(h[n], ea, dtx * Bv[n]);
                yy = fmaf(h[n], Cv[n], yy);
            }
            float zv = z_p[(size_t)t * (2 * D_INNER)];
            float sig = 1.0f / (1.0f + __expf(-zv));
            y_p[(size_t)t * D_INNER] = f2bf((yy + xv * Dd) * (zv * sig));
        }
    } else {
        for (int t = 0; t < CHUNK; ++t) {
            float dt = dt_p[(size_t)t * D_INNER];
            float xv = bf2f(x_p[(size_t)t * D_INNER]);
            const float4* B4 = (const float4*)(Brow + (size_t)t * DBL_N);
            float4 b0 = B4[0], b1 = B4[1], b2 = B4[2], b3 = B4[3];
            float4 c0 = B4[4], c1 = B4[5], c2 = B4[6], c3 = B4[7];
            float Bv[16] = {b0.x,b0.y,b0.z,b0.w, b1.x,b1.y,b1.z,b1.w,
                            b2.x,b2.y,b2.z,b2.w, b3.x,b3.y,b3.z,b3.w};
            float Cv[16] = {c0.x,c0.y,c0.z,c0.w, c1.x,c1.y,c1.z,c1.w,
                            c2.x,c2.y,c2.z,c2.w, c3.x,c3.y,c3.z,c3.w};
            float dtx = dt * xv;
            float yy = 0.f;
            #pragma unroll
            for (int n = 0; n < D_STATE; ++n) {
                float ea = __expf(dt * An[n]);
                h[n] = fmaf(h[n], ea, dtx * Bv[n]);
                yy = fmaf(h[n], Cv[n], yy);
            }
            float zv = z_p[(size_t)t * (2 * D_INNER)];
            float sig = 1.0f / (1.0f + __expf(-zv));
            y_p[(size_t)t * D_INNER] = f2bf((yy + xv * Dd) * (zv * sig));
        }
    }
}

extern "C" void kernel_launch(void* const* d_in, const int* in_sizes, int n_in,
                              void* d_out, int out_size, void* d_ws, size_t ws_size,
                              hipStream_t stream) {
    const float* hs        = (const float*)d_in[0];
    const float* norm_w    = (const float*)d_in[1];
    const float* in_proj_w = (const float*)d_in[2];
    const float* conv_w    = (const float*)d_in[3];
    const float* conv_b    = (const float*)d_in[4];
    const float* x_proj_w  = (const float*)d_in[5];
    const float* dt_proj_w = (const float*)d_in[6];
    const float* dt_proj_b = (const float*)d_in[7];
    const float* A_log     = (const float*)d_in[8];
    const float* Dvec      = (const float*)d_in[9];
    const float* out_proj_w= (const float*)d_in[10];
    float* out = (float*)d_out;

    float* wsf   = (float*)d_ws;
    float* xz    = wsf;                                   // 16,777,216 f
    float* dbl   = xz    + (size_t)16777216;              //    393,216 f
    float* dtb   = dbl   + (size_t)393216;                //  8,388,608 f
    float* sum_a = dtb   + (size_t)8388608;               //  2,097,152 f
    float* sum_h = sum_a + (size_t)2097152;               //  2,097,152 f
    unsigned short* hnorm_bf = (unsigned short*)(sum_h + 2097152); // 4,194,304 us
    unsigned short* ybuf_bf  = hnorm_bf + (size_t)4194304;         // 8,388,608 us
    unsigned short* wi_bf    = ybuf_bf + (size_t)8388608;          // 4,194,304 us
    unsigned short* wo_bf    = wi_bf + (size_t)4194304;            // 2,097,152 us
    unsigned short* xconv_bf = wo_bf + (size_t)2097152;            // 8,388,608 us
    unsigned short* wx_bf    = xconv_bf + (size_t)8388608;         //   262,144 us

    // weight casts
    cast_bf16_kernel<<<(2 * D_INNER * D_MODEL / 4 + 255) / 256, 256, 0, stream>>>(
        (const float4*)in_proj_w, (ushort4*)wi_bf, 2 * D_INNER * D_MODEL / 4);
    cast_bf16_kernel<<<(D_MODEL * D_INNER / 4 + 255) / 256, 256, 0, stream>>>(
        (const float4*)out_proj_w, (ushort4*)wo_bf, D_MODEL * D_INNER / 4);
    cast_bf16_kernel<<<(DBL_N * D_INNER / 4 + 255) / 256, 256, 0, stream>>>(
        (const float4*)x_proj_w, (ushort4*)wx_bf, DBL_N * D_INNER / 4);

    // 1. RMSNorm -> bf16
    rmsnorm_kernel<<<NTOK, 256, 0, stream>>>(hs, norm_w, hnorm_bf);
    // 2. in_proj (MFMA): xz = hnorm @ in_proj_w^T
    mfma_gemm_kernel<<<dim3((2 * D_INNER) / 128, NTOK / 128), 256, 0, stream>>>(
        hnorm_bf, D_MODEL, wi_bf, D_MODEL, xz, 2 * D_INNER, D_MODEL, 2 * D_INNER, nullptr, 0);
    // 3. depthwise causal conv + SiLU -> xconv (bf16)
    conv_silu_kernel<<<(NTOK * D_INNER) / 256, 256, 0, stream>>>(
        xz, conv_w, conv_b, xconv_bf);
    // 4. x_proj (MFMA, N=96 padded to 128): dbl = silu(conv(x)) @ x_proj_w^T
    mfma_gemm_kernel<<<dim3(1, NTOK / 128), 256, 0, stream>>>(
        xconv_bf, D_INNER, wx_bf, D_INNER, dbl, DBL_N, D_INNER, DBL_N, nullptr, 0);
    // 5. dt_proj + bias + softplus
    gemm_kernel<<<dim3(32, 64), 256, 0, stream>>>(
        dbl, DBL_N, dt_proj_w, DT_RANK, dtb, D_INNER,
        NTOK, D_INNER, DT_RANK, dt_proj_b, 1);
    // 6. scan: phase1 -> carry -> phase3
    scan_phase1_kernel<<<dim3(NCHUNK, D_INNER / 256, B_SZ), 256, 0, stream>>>(
        dtb, xconv_bf, dbl, A_log, sum_a, sum_h);
    scan_carry_kernel<<<(B_SZ * D_INNER * D_STATE) / 256, 256, 0, stream>>>(sum_a, sum_h);
    scan_phase3_kernel<<<dim3(NCHUNK, D_INNER / 256, B_SZ), 256, 0, stream>>>(
        dtb, xconv_bf, xz, dbl, A_log, Dvec, sum_h, ybuf_bf);
    // 7. out_proj (MFMA) + residual -> d_out
    mfma_gemm_kernel<<<dim3(D_MODEL / 128, NTOK / 128), 256, 0, stream>>>(
        ybuf_bf, D_INNER, wo_bf, D_INNER, out, D_MODEL, D_INNER, D_MODEL, hs, D_MODEL);
}

// Round 6
// 403.187 us; speedup vs baseline: 7.6273x; 1.0468x over previous
//
#include <hip/hip_runtime.h>
#include <math.h>

#define D_MODEL 1024
#define D_INNER 2048
#define D_STATE 16
#define D_CONV  4
#define DT_RANK 64
#define B_SZ    2
#define SEQ     2048
#define NTOK    (B_SZ*SEQ)            // 4096
#define DBL_N   (DT_RANK + 2*D_STATE) // 96
#define CHUNK   64
#define NCHUNK  (SEQ/CHUNK)           // 32

typedef __attribute__((ext_vector_type(8))) short short8;
typedef __attribute__((ext_vector_type(4))) float f32x4;

__device__ __forceinline__ unsigned short f2bf(float f) {
    union { float f; unsigned int u; } v; v.f = f;
    unsigned int r = v.u + 0x7fff + ((v.u >> 16) & 1);   // RNE
    return (unsigned short)(r >> 16);
}
__device__ __forceinline__ float bf2f(unsigned short u) {
    union { unsigned int u; float f; } v; v.u = ((unsigned int)u) << 16;
    return v.f;
}

// ---------------- RMSNorm: one block per token, bf16 output ----------------
__global__ __launch_bounds__(256) void rmsnorm_kernel(
    const float* __restrict__ h, const float* __restrict__ w, unsigned short* __restrict__ out)
{
    int tok = blockIdx.x;
    const float4* row = (const float4*)(h + (size_t)tok * D_MODEL);
    float4 v = row[threadIdx.x];
    float ss = v.x*v.x + v.y*v.y + v.z*v.z + v.w*v.w;
    #pragma unroll
    for (int off = 32; off >= 1; off >>= 1) ss += __shfl_down(ss, off, 64);
    __shared__ float red[4];
    int wave = threadIdx.x >> 6, lane = threadIdx.x & 63;
    if (lane == 0) red[wave] = ss;
    __syncthreads();
    float tot = red[0] + red[1] + red[2] + red[3];
    float scale = rsqrtf(tot * (1.0f / D_MODEL) + 1e-5f);
    float4 wv = ((const float4*)w)[threadIdx.x];
    ushort4 o;
    o.x = f2bf(v.x * scale * wv.x);
    o.y = f2bf(v.y * scale * wv.y);
    o.z = f2bf(v.z * scale * wv.z);
    o.w = f2bf(v.w * scale * wv.w);
    ((ushort4*)(out + (size_t)tok * D_MODEL))[threadIdx.x] = o;
}

// ---------------- fp32 -> bf16 cast ----------------
__global__ __launch_bounds__(256) void cast_bf16_kernel(
    const float4* __restrict__ in, ushort4* __restrict__ out, int n4)
{
    int i = blockIdx.x * 256 + threadIdx.x;
    if (i < n4) {
        float4 v = in[i];
        ushort4 o; o.x = f2bf(v.x); o.y = f2bf(v.y); o.z = f2bf(v.z); o.w = f2bf(v.w);
        out[i] = o;
    }
}

// ---------------- bf16 MFMA GEMM with XOR-swizzled LDS ----------------
// C(fp32, opt) and/or Cbf(bf16, opt) = act(A @ W^T + bias) + add
// grid.z = split-K segment (kLen per segment); C += seg*segStride.
// LDS swizzle: lane stores global k-chunk (cl ^ ((r>>1)&3)) into slot cl;
// reader fetches slot (quad ^ ((frow>>1)&3)) -> 2-way bank aliasing only (free).
__global__ __launch_bounds__(256) void mfma_gemm_kernel(
    const unsigned short* __restrict__ A, int lda,
    const unsigned short* __restrict__ W, int ldw,
    float* __restrict__ C, int ldc,
    unsigned short* __restrict__ Cbf, int ldcbf,
    int kLen, int Nmax,
    const float* __restrict__ bias,
    const float* __restrict__ add, int ldadd,
    int act, size_t segStride)
{
    __shared__ __align__(16) unsigned short As[128 * 32];
    __shared__ __align__(16) unsigned short Bs[128 * 32];
    const int bm = blockIdx.y * 128;
    const int bn = blockIdx.x * 128;
    const int kBeg = blockIdx.z * kLen;
    const int tid = threadIdx.x;
    const int lane = tid & 63;
    const int wave = tid >> 6;
    const int wm = (wave >> 1) * 64;
    const int wn = (wave & 1) * 64;
    const int frow = lane & 15;
    const int quad = lane >> 4;
    const int sw = (frow >> 1) & 3;          // read-side unswizzle

    if (C) C += blockIdx.z * segStride;

    f32x4 acc[4][4];
    #pragma unroll
    for (int i = 0; i < 4; ++i)
        #pragma unroll
        for (int j = 0; j < 4; ++j)
            acc[i][j] = (f32x4){0.f, 0.f, 0.f, 0.f};

    for (int k0 = kBeg; k0 < kBeg + kLen; k0 += 32) {
        __syncthreads();
        #pragma unroll
        for (int i = 0; i < 2; ++i) {
            int q = (wave * 2 + i) * 64 + lane;
            int r = q >> 2, cl = q & 3;
            int cg = cl ^ ((r >> 1) & 3);                 // source swizzle
            const unsigned short* ga = A + (size_t)(bm + r) * lda + k0 + cg * 8;
            const unsigned short* gb = W + (size_t)(bn + r) * ldw + k0 + cg * 8;
            __builtin_amdgcn_global_load_lds(
                (const __attribute__((address_space(1))) void*)ga,
                (__attribute__((address_space(3))) void*)(As + (wave * 2 + i) * 512),
                16, 0, 0);
            __builtin_amdgcn_global_load_lds(
                (const __attribute__((address_space(1))) void*)gb,
                (__attribute__((address_space(3))) void*)(Bs + (wave * 2 + i) * 512),
                16, 0, 0);
        }
        __syncthreads();
        short8 af[4], bf[4];
        #pragma unroll
        for (int i = 0; i < 4; ++i)
            af[i] = *(const short8*)&As[(wm + i * 16 + frow) * 32 + (quad ^ sw) * 8];
        #pragma unroll
        for (int j = 0; j < 4; ++j)
            bf[j] = *(const short8*)&Bs[(wn + j * 16 + frow) * 32 + (quad ^ sw) * 8];
        #pragma unroll
        for (int i = 0; i < 4; ++i)
            #pragma unroll
            for (int j = 0; j < 4; ++j)
                acc[i][j] = __builtin_amdgcn_mfma_f32_16x16x32_bf16(
                    af[i], bf[j], acc[i][j], 0, 0, 0);
    }

    // epilogue: C/D layout col=lane&15, row=quad*4+reg
    #pragma unroll
    for (int i = 0; i < 4; ++i) {
        #pragma unroll
        for (int r = 0; r < 4; ++r) {
            int row = bm + wm + i * 16 + quad * 4 + r;
            #pragma unroll
            for (int j = 0; j < 4; ++j) {
                int col = bn + wn + j * 16 + frow;
                if (col < Nmax) {
                    float v = acc[i][j][r];
                    if (bias) v += bias[col];
                    if (act == 1) v = (v > 20.0f) ? v : log1pf(__expf(v));
                    if (add) v += add[(size_t)row * ldadd + col];
                    if (C)   C[(size_t)row * ldc + col] = v;
                    if (Cbf) Cbf[(size_t)row * ldcbf + col] = f2bf(v);
                }
            }
        }
    }
}

// ---------------- x_proj split-K reduce + dt_r bf16 extract ----------------
__global__ __launch_bounds__(256) void reduce_xproj_kernel(
    const float* __restrict__ part, float* __restrict__ dbl,
    unsigned short* __restrict__ dtr)
{
    const int N = NTOK * DBL_N;
    int idx = blockIdx.x * 256 + threadIdx.x;
    if (idx >= N) return;
    float s = part[idx] + part[idx + N] + part[idx + 2 * N] + part[idx + 3 * N];
    dbl[idx] = s;
    unsigned int col = (unsigned int)idx % DBL_N;
    if (col < DT_RANK) {
        unsigned int tok = (unsigned int)idx / DBL_N;
        dtr[(size_t)tok * DT_RANK + col] = f2bf(s);
    }
}

// ---------------- Causal depthwise conv (k=4) + SiLU, bf16 in/out ----------------
__global__ __launch_bounds__(256) void conv_silu_kernel(
    const unsigned short* __restrict__ xz, const float* __restrict__ cw,
    const float* __restrict__ cb, unsigned short* __restrict__ out_bf)
{
    int idx = blockIdx.x * 256 + threadIdx.x;   // over NTOK*D_INNER
    int d = idx & (D_INNER - 1);
    int t = (idx >> 11) & (SEQ - 1);
    int b = idx >> 22;
    const unsigned short* xcol = xz + (size_t)b * SEQ * (2 * D_INNER) + d;
    float w0 = cw[d * 4 + 0], w1 = cw[d * 4 + 1], w2 = cw[d * 4 + 2], w3 = cw[d * 4 + 3];
    float acc = cb[d];
    if (t >= 3) acc = fmaf(bf2f(xcol[(size_t)(t - 3) * (2 * D_INNER)]), w0, acc);
    if (t >= 2) acc = fmaf(bf2f(xcol[(size_t)(t - 2) * (2 * D_INNER)]), w1, acc);
    if (t >= 1) acc = fmaf(bf2f(xcol[(size_t)(t - 1) * (2 * D_INNER)]), w2, acc);
    acc = fmaf(bf2f(xcol[(size_t)t * (2 * D_INNER)]), w3, acc);
    float sig = 1.0f / (1.0f + __expf(-acc));
    out_bf[(size_t)(b * SEQ + t) * D_INNER + d] = f2bf(acc * sig);
}

// ---------------- Scan phase 1: per-chunk summaries, one thread per d ----------------
__global__ __launch_bounds__(256) void scan_phase1_kernel(
    const float* __restrict__ dtb, const unsigned short* __restrict__ xconv,
    const float* __restrict__ dbl, const float* __restrict__ A_log,
    float* __restrict__ sum_a, float* __restrict__ sum_h)
{
    const int d = blockIdx.y * 256 + threadIdx.x;
    const int c = blockIdx.x;
    const int b = blockIdx.z;
    const int t0 = c * CHUNK;

    float An[D_STATE];
    bool fast = true;
    #pragma unroll
    for (int n = 0; n < D_STATE; ++n) {
        An[n] = -__expf(A_log[d * D_STATE + n]);
        fast = fast && (fabsf(An[n] + (float)(n + 1)) < 2e-3f);
    }
    const float* dt_p = dtb + ((size_t)b * SEQ + t0) * D_INNER + d;
    const unsigned short* x_p = xconv + ((size_t)b * SEQ + t0) * D_INNER + d;
    const float* Brow = dbl + ((size_t)b * SEQ + t0) * DBL_N + DT_RANK;   // wave-uniform

    float h[D_STATE];
    #pragma unroll
    for (int n = 0; n < D_STATE; ++n) h[n] = 0.f;
    float sumdt = 0.f;

    if (fast) {
        for (int t = 0; t < CHUNK; ++t) {
            float dt = dt_p[(size_t)t * D_INNER];
            float xv = bf2f(x_p[(size_t)t * D_INNER]);
            const float4* B4 = (const float4*)(Brow + (size_t)t * DBL_N);
            float4 b0 = B4[0], b1 = B4[1], b2 = B4[2], b3 = B4[3];
            float Bv[16] = {b0.x,b0.y,b0.z,b0.w, b1.x,b1.y,b1.z,b1.w,
                            b2.x,b2.y,b2.z,b2.w, b3.x,b3.y,b3.z,b3.w};
            sumdt += dt;
            float e1 = __expf(-dt);
            float dtx = dt * xv;
            float ea = 1.f;
            #pragma unroll
            for (int n = 0; n < D_STATE; ++n) {
                ea *= e1;
                h[n] = fmaf(h[n], ea, dtx * Bv[n]);
            }
        }
    } else {
        for (int t = 0; t < CHUNK; ++t) {
            float dt = dt_p[(size_t)t * D_INNER];
            float xv = bf2f(x_p[(size_t)t * D_INNER]);
            const float4* B4 = (const float4*)(Brow + (size_t)t * DBL_N);
            float4 b0 = B4[0], b1 = B4[1], b2 = B4[2], b3 = B4[3];
            float Bv[16] = {b0.x,b0.y,b0.z,b0.w, b1.x,b1.y,b1.z,b1.w,
                            b2.x,b2.y,b2.z,b2.w, b3.x,b3.y,b3.z,b3.w};
            sumdt += dt;
            float dtx = dt * xv;
            #pragma unroll
            for (int n = 0; n < D_STATE; ++n) {
                float ea = __expf(dt * An[n]);
                h[n] = fmaf(h[n], ea, dtx * Bv[n]);
            }
        }
    }

    float a[D_STATE];
    if (fast) {
        float E = __expf(-sumdt);
        float ea = 1.f;
        #pragma unroll
        for (int n = 0; n < D_STATE; ++n) { ea *= E; a[n] = ea; }
    } else {
        #pragma unroll
        for (int n = 0; n < D_STATE; ++n) a[n] = __expf(An[n] * sumdt);
    }
    size_t base = (((size_t)b * D_INNER + d) * NCHUNK + c) * D_STATE;
    #pragma unroll
    for (int i = 0; i < 4; ++i) {
        ((float4*)(sum_a + base))[i] = (float4){a[4*i], a[4*i+1], a[4*i+2], a[4*i+3]};
        ((float4*)(sum_h + base))[i] = (float4){h[4*i], h[4*i+1], h[4*i+2], h[4*i+3]};
    }
}

// ---------------- Scan phase 2: inter-chunk carry (in-place over sum_h) ----------------
__global__ __launch_bounds__(256) void scan_carry_kernel(
    const float* __restrict__ sum_a, float* __restrict__ sum_h)
{
    size_t g = (size_t)blockIdx.x * 256 + threadIdx.x;   // (b,d,n): 65536 groups
    size_t bd = g >> 4;
    int n = (int)(g & 15);
    size_t base = bd * NCHUNK * D_STATE + n;
    float hh = 0.f;
    for (int c = 0; c < NCHUNK; ++c) {
        size_t idx = base + (size_t)c * D_STATE;
        float a = sum_a[idx];
        float hp = sum_h[idx];
        sum_h[idx] = hh;
        hh = fmaf(hh, a, hp);
    }
}

// ---------------- Scan phase 3: re-scan with carry, emit y (bf16) ----------------
__global__ __launch_bounds__(256) void scan_phase3_kernel(
    const float* __restrict__ dtb, const unsigned short* __restrict__ xconv,
    const unsigned short* __restrict__ xz, const float* __restrict__ dbl,
    const float* __restrict__ A_log, const float* __restrict__ Dvec,
    const float* __restrict__ hinit, unsigned short* __restrict__ y)
{
    const int d = blockIdx.y * 256 + threadIdx.x;
    const int c = blockIdx.x;
    const int b = blockIdx.z;
    const int t0 = c * CHUNK;

    float An[D_STATE];
    bool fast = true;
    #pragma unroll
    for (int n = 0; n < D_STATE; ++n) {
        An[n] = -__expf(A_log[d * D_STATE + n]);
        fast = fast && (fabsf(An[n] + (float)(n + 1)) < 2e-3f);
    }
    const float Dd = Dvec[d];
    const float* dt_p = dtb + ((size_t)b * SEQ + t0) * D_INNER + d;
    const unsigned short* x_p = xconv + ((size_t)b * SEQ + t0) * D_INNER + d;
    const unsigned short* z_p = xz + ((size_t)b * SEQ + t0) * (2 * D_INNER) + D_INNER + d;
    const float* Brow = dbl + ((size_t)b * SEQ + t0) * DBL_N + DT_RANK;
    unsigned short* y_p = y + ((size_t)b * SEQ + t0) * D_INNER + d;

    size_t base = (((size_t)b * D_INNER + d) * NCHUNK + c) * D_STATE;
    float h[D_STATE];
    #pragma unroll
    for (int i = 0; i < 4; ++i) {
        float4 hv = ((const float4*)(hinit + base))[i];
        h[4*i] = hv.x; h[4*i+1] = hv.y; h[4*i+2] = hv.z; h[4*i+3] = hv.w;
    }

    if (fast) {
        for (int t = 0; t < CHUNK; ++t) {
            float dt = dt_p[(size_t)t * D_INNER];
            float xv = bf2f(x_p[(size_t)t * D_INNER]);
            const float4* B4 = (const float4*)(Brow + (size_t)t * DBL_N);
            float4 b0 = B4[0], b1 = B4[1], b2 = B4[2], b3 = B4[3];
            float4 c0 = B4[4], c1 = B4[5], c2 = B4[6], c3 = B4[7];
            float Bv[16] = {b0.x,b0.y,b0.z,b0.w, b1.x,b1.y,b1.z,b1.w,
                            b2.x,b2.y,b2.z,b2.w, b3.x,b3.y,b3.z,b3.w};
            float Cv[16] = {c0.x,c0.y,c0.z,c0.w, c1.x,c1.y,c1.z,c1.w,
                            c2.x,c2.y,c2.z,c2.w, c3.x,c3.y,c3.z,c3.w};
            float e1 = __expf(-dt);
            float dtx = dt * xv;
            float ea = 1.f, yy = 0.f;
            #pragma unroll
            for (int n = 0; n < D_STATE; ++n) {
                ea *= e1;
                h[n] = fmaf(h[n], ea, dtx * Bv[n]);
                yy = fmaf(h[n], Cv[n], yy);
            }
            float zv = bf2f(z_p[(size_t)t * (2 * D_INNER)]);
            float sig = 1.0f / (1.0f + __expf(-zv));
            y_p[(size_t)t * D_INNER] = f2bf((yy + xv * Dd) * (zv * sig));
        }
    } else {
        for (int t = 0; t < CHUNK; ++t) {
            float dt = dt_p[(size_t)t * D_INNER];
            float xv = bf2f(x_p[(size_t)t * D_INNER]);
            const float4* B4 = (const float4*)(Brow + (size_t)t * DBL_N);
            float4 b0 = B4[0], b1 = B4[1], b2 = B4[2], b3 = B4[3];
            float4 c0 = B4[4], c1 = B4[5], c2 = B4[6], c3 = B4[7];
            float Bv[16] = {b0.x,b0.y,b0.z,b0.w, b1.x,b1.y,b1.z,b1.w,
                            b2.x,b2.y,b2.z,b2.w, b3.x,b3.y,b3.z,b3.w};
            float Cv[16] = {c0.x,c0.y,c0.z,c0.w, c1.x,c1.y,c1.z,c1.w,
                            c2.x,c2.y,c2.z,c2.w, c3.x,c3.y,c3.z,c3.w};
            float dtx = dt * xv;
            float yy = 0.f;
            #pragma unroll
            for (int n = 0; n < D_STATE; ++n) {
                float ea = __expf(dt * An[n]);
                h[n] = fmaf(h[n], ea, dtx * Bv[n]);
                yy = fmaf(h[n], Cv[n], yy);
            }
            float zv = bf2f(z_p[(size_t)t * (2 * D_INNER)]);
            float sig = 1.0f / (1.0f + __expf(-zv));
            y_p[(size_t)t * D_INNER] = f2bf((yy + xv * Dd) * (zv * sig));
        }
    }
}

extern "C" void kernel_launch(void* const* d_in, const int* in_sizes, int n_in,
                              void* d_out, int out_size, void* d_ws, size_t ws_size,
                              hipStream_t stream) {
    const float* hs        = (const float*)d_in[0];
    const float* norm_w    = (const float*)d_in[1];
    const float* in_proj_w = (const float*)d_in[2];
    const float* conv_w    = (const float*)d_in[3];
    const float* conv_b    = (const float*)d_in[4];
    const float* x_proj_w  = (const float*)d_in[5];
    const float* dt_proj_w = (const float*)d_in[6];
    const float* dt_proj_b = (const float*)d_in[7];
    const float* A_log     = (const float*)d_in[8];
    const float* Dvec      = (const float*)d_in[9];
    const float* out_proj_w= (const float*)d_in[10];
    float* out = (float*)d_out;

    float* wsf      = (float*)d_ws;
    float* dbl      = wsf;                                //   393,216 f
    float* dbl_part = dbl      + (size_t)393216;          // 1,572,864 f
    float* dtb      = dbl_part + (size_t)1572864;         // 8,388,608 f
    float* sum_a    = dtb      + (size_t)8388608;         // 2,097,152 f
    float* sum_h    = sum_a    + (size_t)2097152;         // 2,097,152 f
    unsigned short* xz_bf    = (unsigned short*)(sum_h + 2097152); // 16,777,216 us
    unsigned short* xconv_bf = xz_bf    + (size_t)16777216;        //  8,388,608 us
    unsigned short* hnorm_bf = xconv_bf + (size_t)8388608;         //  4,194,304 us
    unsigned short* ybuf_bf  = hnorm_bf + (size_t)4194304;         //  8,388,608 us
    unsigned short* wi_bf    = ybuf_bf  + (size_t)8388608;         //  4,194,304 us
    unsigned short* wo_bf    = wi_bf    + (size_t)4194304;         //  2,097,152 us
    unsigned short* wx_bf    = wo_bf    + (size_t)2097152;         //    262,144 us (128-row pad)
    unsigned short* wdt_bf   = wx_bf    + (size_t)262144;          //    131,072 us
    unsigned short* dtr_bf   = wdt_bf   + (size_t)131072;          //    262,144 us

    // weight casts
    cast_bf16_kernel<<<(2 * D_INNER * D_MODEL / 4 + 255) / 256, 256, 0, stream>>>(
        (const float4*)in_proj_w, (ushort4*)wi_bf, 2 * D_INNER * D_MODEL / 4);
    cast_bf16_kernel<<<(D_MODEL * D_INNER / 4 + 255) / 256, 256, 0, stream>>>(
        (const float4*)out_proj_w, (ushort4*)wo_bf, D_MODEL * D_INNER / 4);
    cast_bf16_kernel<<<(DBL_N * D_INNER / 4 + 255) / 256, 256, 0, stream>>>(
        (const float4*)x_proj_w, (ushort4*)wx_bf, DBL_N * D_INNER / 4);
    cast_bf16_kernel<<<(D_INNER * DT_RANK / 4 + 255) / 256, 256, 0, stream>>>(
        (const float4*)dt_proj_w, (ushort4*)wdt_bf, D_INNER * DT_RANK / 4);

    // 1. RMSNorm -> bf16
    rmsnorm_kernel<<<NTOK, 256, 0, stream>>>(hs, norm_w, hnorm_bf);
    // 2. in_proj (MFMA): xz_bf = hnorm @ in_proj_w^T  (bf16 out)
    mfma_gemm_kernel<<<dim3((2 * D_INNER) / 128, NTOK / 128), 256, 0, stream>>>(
        hnorm_bf, D_MODEL, wi_bf, D_MODEL, nullptr, 0, xz_bf, 2 * D_INNER,
        D_MODEL, 2 * D_INNER, nullptr, nullptr, 0, 0, 0);
    // 3. depthwise causal conv + SiLU (bf16 in/out)
    conv_silu_kernel<<<(NTOK * D_INNER) / 256, 256, 0, stream>>>(
        xz_bf, conv_w, conv_b, xconv_bf);
    // 4. x_proj (MFMA, split-K x4): dbl_part[seg] = xconv @ x_proj_w^T (N=96)
    mfma_gemm_kernel<<<dim3(1, NTOK / 128, 4), 256, 0, stream>>>(
        xconv_bf, D_INNER, wx_bf, D_INNER, dbl_part, DBL_N, nullptr, 0,
        D_INNER / 4, DBL_N, nullptr, nullptr, 0, 0, (size_t)NTOK * DBL_N);
    reduce_xproj_kernel<<<(NTOK * DBL_N + 255) / 256, 256, 0, stream>>>(
        dbl_part, dbl, dtr_bf);
    // 5. dt_proj (MFMA) + bias + softplus -> dtb (fp32)
    mfma_gemm_kernel<<<dim3(D_INNER / 128, NTOK / 128), 256, 0, stream>>>(
        dtr_bf, DT_RANK, wdt_bf, DT_RANK, dtb, D_INNER, nullptr, 0,
        DT_RANK, D_INNER, dt_proj_b, nullptr, 0, 1, 0);
    // 6. scan: phase1 -> carry -> phase3
    scan_phase1_kernel<<<dim3(NCHUNK, D_INNER / 256, B_SZ), 256, 0, stream>>>(
        dtb, xconv_bf, dbl, A_log, sum_a, sum_h);
    scan_carry_kernel<<<(B_SZ * D_INNER * D_STATE) / 256, 256, 0, stream>>>(sum_a, sum_h);
    scan_phase3_kernel<<<dim3(NCHUNK, D_INNER / 256, B_SZ), 256, 0, stream>>>(
        dtb, xconv_bf, xz_bf, dbl, A_log, Dvec, sum_h, ybuf_bf);
    // 7. out_proj (MFMA) + residual -> d_out
    mfma_gemm_kernel<<<dim3(D_MODEL / 128, NTOK / 128), 256, 0, stream>>>(
        ybuf_bf, D_INNER, wo_bf, D_INNER, out, D_MODEL, nullptr, 0,
        D_INNER, D_MODEL, nullptr, hs, D_MODEL, 0, 0);
}

// Round 7
// 400.686 us; speedup vs baseline: 7.6749x; 1.0062x over previous
//
#include <hip/hip_runtime.h>
#include <math.h>

#define D_MODEL 1024
#define D_INNER 2048
#define D_STATE 16
#define D_CONV  4
#define DT_RANK 64
#define B_SZ    2
#define SEQ     2048
#define NTOK    (B_SZ*SEQ)            // 4096
#define DBL_N   (DT_RANK + 2*D_STATE) // 96
#define CHUNK   64
#define NCHUNK  (SEQ/CHUNK)           // 32

typedef __attribute__((ext_vector_type(8))) short short8;
typedef __attribute__((ext_vector_type(4))) float f32x4;

__device__ __forceinline__ unsigned short f2bf(float f) {
    union { float f; unsigned int u; } v; v.f = f;
    unsigned int r = v.u + 0x7fff + ((v.u >> 16) & 1);   // RNE
    return (unsigned short)(r >> 16);
}
__device__ __forceinline__ float bf2f(unsigned short u) {
    union { unsigned int u; float f; } v; v.u = ((unsigned int)u) << 16;
    return v.f;
}
// swizzled column: permute 16B chunks (8 bf16) within each 64B group by row parity
__device__ __forceinline__ int swz_col(int r, int k) {
    int p = (((k >> 3) ^ (r >> 1)) & 3) << 3;
    return (k & ~0x18) | p;
}

// ---------------- RMSNorm: one block per token, bf16 swizzled output ----------------
__global__ __launch_bounds__(256) void rmsnorm_kernel(
    const float* __restrict__ h, const float* __restrict__ w, unsigned short* __restrict__ out)
{
    int tok = blockIdx.x;
    const float4* row = (const float4*)(h + (size_t)tok * D_MODEL);
    float4 v = row[threadIdx.x];
    float ss = v.x*v.x + v.y*v.y + v.z*v.z + v.w*v.w;
    #pragma unroll
    for (int off = 32; off >= 1; off >>= 1) ss += __shfl_down(ss, off, 64);
    __shared__ float red[4];
    int wave = threadIdx.x >> 6, lane = threadIdx.x & 63;
    if (lane == 0) red[wave] = ss;
    __syncthreads();
    float tot = red[0] + red[1] + red[2] + red[3];
    float scale = rsqrtf(tot * (1.0f / D_MODEL) + 1e-5f);
    float4 wv = ((const float4*)w)[threadIdx.x];
    ushort4 o;
    o.x = f2bf(v.x * scale * wv.x);
    o.y = f2bf(v.y * scale * wv.y);
    o.z = f2bf(v.z * scale * wv.z);
    o.w = f2bf(v.w * scale * wv.w);
    int col = swz_col(tok, threadIdx.x * 4);
    *(ushort4*)(out + (size_t)tok * D_MODEL + col) = o;
}

// ---------------- fused fp32 -> bf16 swizzled cast for 4 weight matrices ----------------
// n* in float4 units; ldlog* = log2(row length in elements)
__global__ __launch_bounds__(256) void cast4_swz_kernel(
    const float4* __restrict__ s0, unsigned short* __restrict__ d0, int n0, int l0,
    const float4* __restrict__ s1, unsigned short* __restrict__ d1, int n1, int l1,
    const float4* __restrict__ s2, unsigned short* __restrict__ d2, int n2, int l2,
    const float4* __restrict__ s3, unsigned short* __restrict__ d3, int n3, int l3)
{
    int i = blockIdx.x * 256 + threadIdx.x;
    const float4* s; unsigned short* d; int ll;
    if (i < n0) { s = s0; d = d0; ll = l0; }
    else if ((i -= n0) < n1) { s = s1; d = d1; ll = l1; }
    else if ((i -= n1) < n2) { s = s2; d = d2; ll = l2; }
    else if ((i -= n2) < n3) { s = s3; d = d3; ll = l3; }
    else return;
    int e = i * 4;
    int r = e >> ll;
    int k = e & ((1 << ll) - 1);
    float4 v = s[i];
    ushort4 o; o.x = f2bf(v.x); o.y = f2bf(v.y); o.z = f2bf(v.z); o.w = f2bf(v.w);
    *(ushort4*)(d + ((size_t)r << ll) + swz_col(r, k)) = o;
}

// ---------------- bf16 MFMA GEMM: linear coalesced staging + swizzle-aware reads ----
// Inputs A,W are PRE-SWIZZLED (swz_col). C(fp32,opt)/Cbf(bf16,opt) outputs are linear.
__global__ __launch_bounds__(256) void mfma_gemm_kernel(
    const unsigned short* __restrict__ A, int lda,
    const unsigned short* __restrict__ W, int ldw,
    float* __restrict__ C, int ldc,
    unsigned short* __restrict__ Cbf, int ldcbf,
    int kLen, int Nmax,
    const float* __restrict__ bias,
    const float* __restrict__ add, int ldadd,
    int act, size_t segStride)
{
    __shared__ __align__(16) unsigned short As[128 * 32];
    __shared__ __align__(16) unsigned short Bs[128 * 32];
    const int bm = blockIdx.y * 128;
    const int bn = blockIdx.x * 128;
    const int kBeg = blockIdx.z * kLen;
    const int tid = threadIdx.x;
    const int lane = tid & 63;
    const int wave = tid >> 6;
    const int wm = (wave >> 1) * 64;
    const int wn = (wave & 1) * 64;
    const int frow = lane & 15;
    const int quad = lane >> 4;
    const int sw = (frow >> 1) & 3;          // read-side unswizzle (data pre-swizzled)

    if (C) C += blockIdx.z * segStride;

    f32x4 acc[4][4];
    #pragma unroll
    for (int i = 0; i < 4; ++i)
        #pragma unroll
        for (int j = 0; j < 4; ++j)
            acc[i][j] = (f32x4){0.f, 0.f, 0.f, 0.f};

    for (int k0 = kBeg; k0 < kBeg + kLen; k0 += 32) {
        __syncthreads();
        #pragma unroll
        for (int i = 0; i < 2; ++i) {
            int q = (wave * 2 + i) * 64 + lane;
            int r = q >> 2, cl = q & 3;                   // linear: full coalescing
            const unsigned short* ga = A + (size_t)(bm + r) * lda + k0 + cl * 8;
            const unsigned short* gb = W + (size_t)(bn + r) * ldw + k0 + cl * 8;
            __builtin_amdgcn_global_load_lds(
                (const __attribute__((address_space(1))) void*)ga,
                (__attribute__((address_space(3))) void*)(As + (wave * 2 + i) * 512),
                16, 0, 0);
            __builtin_amdgcn_global_load_lds(
                (const __attribute__((address_space(1))) void*)gb,
                (__attribute__((address_space(3))) void*)(Bs + (wave * 2 + i) * 512),
                16, 0, 0);
        }
        __syncthreads();
        short8 af[4], bf[4];
        #pragma unroll
        for (int i = 0; i < 4; ++i)
            af[i] = *(const short8*)&As[(wm + i * 16 + frow) * 32 + (quad ^ sw) * 8];
        #pragma unroll
        for (int j = 0; j < 4; ++j)
            bf[j] = *(const short8*)&Bs[(wn + j * 16 + frow) * 32 + (quad ^ sw) * 8];
        #pragma unroll
        for (int i = 0; i < 4; ++i)
            #pragma unroll
            for (int j = 0; j < 4; ++j)
                acc[i][j] = __builtin_amdgcn_mfma_f32_16x16x32_bf16(
                    af[i], bf[j], acc[i][j], 0, 0, 0);
    }

    // epilogue: C/D layout col=lane&15, row=quad*4+reg
    #pragma unroll
    for (int i = 0; i < 4; ++i) {
        #pragma unroll
        for (int r = 0; r < 4; ++r) {
            int row = bm + wm + i * 16 + quad * 4 + r;
            #pragma unroll
            for (int j = 0; j < 4; ++j) {
                int col = bn + wn + j * 16 + frow;
                if (col < Nmax) {
                    float v = acc[i][j][r];
                    if (bias) v += bias[col];
                    if (act == 1) v = (v > 20.0f) ? v : log1pf(__expf(v));
                    if (add) v += add[(size_t)row * ldadd + col];
                    if (C)   C[(size_t)row * ldc + col] = v;
                    if (Cbf) Cbf[(size_t)row * ldcbf + col] = f2bf(v);
                }
            }
        }
    }
}

// ---------------- x_proj split-K reduce + dt_r bf16 swizzled extract ----------------
__global__ __launch_bounds__(256) void reduce_xproj_kernel(
    const float* __restrict__ part, float* __restrict__ dbl,
    unsigned short* __restrict__ dtr)
{
    const int N = NTOK * DBL_N;
    int idx = blockIdx.x * 256 + threadIdx.x;
    if (idx >= N) return;
    float s = part[idx] + part[idx + N] + part[idx + 2 * N] + part[idx + 3 * N];
    dbl[idx] = s;
    unsigned int col = (unsigned int)idx % DBL_N;
    if (col < DT_RANK) {
        unsigned int tok = (unsigned int)idx / DBL_N;
        dtr[(size_t)tok * DT_RANK + swz_col((int)tok, (int)col)] = f2bf(s);
    }
}

// ---------------- Causal depthwise conv (k=4) + SiLU, bf16 in, swizzled bf16 out ----
__global__ __launch_bounds__(256) void conv_silu_kernel(
    const unsigned short* __restrict__ xz, const float* __restrict__ cw,
    const float* __restrict__ cb, unsigned short* __restrict__ out_bf)
{
    int idx = blockIdx.x * 256 + threadIdx.x;   // over NTOK*D_INNER
    int d = idx & (D_INNER - 1);
    int t = (idx >> 11) & (SEQ - 1);
    int b = idx >> 22;
    const unsigned short* xcol = xz + (size_t)b * SEQ * (2 * D_INNER) + d;
    float w0 = cw[d * 4 + 0], w1 = cw[d * 4 + 1], w2 = cw[d * 4 + 2], w3 = cw[d * 4 + 3];
    float acc = cb[d];
    if (t >= 3) acc = fmaf(bf2f(xcol[(size_t)(t - 3) * (2 * D_INNER)]), w0, acc);
    if (t >= 2) acc = fmaf(bf2f(xcol[(size_t)(t - 2) * (2 * D_INNER)]), w1, acc);
    if (t >= 1) acc = fmaf(bf2f(xcol[(size_t)(t - 1) * (2 * D_INNER)]), w2, acc);
    acc = fmaf(bf2f(xcol[(size_t)t * (2 * D_INNER)]), w3, acc);
    float sig = 1.0f / (1.0f + __expf(-acc));
    out_bf[(size_t)(b * SEQ + t) * D_INNER + swz_col(t, d)] = f2bf(acc * sig);
}

// ---------------- Scan phase 1: per-chunk summaries, one thread per d ----------------
__global__ __launch_bounds__(256) void scan_phase1_kernel(
    const float* __restrict__ dtb, const unsigned short* __restrict__ xconv,
    const float* __restrict__ dbl, const float* __restrict__ A_log,
    float* __restrict__ sum_a, float* __restrict__ sum_h)
{
    const int d = blockIdx.y * 256 + threadIdx.x;
    const int c = blockIdx.x;
    const int b = blockIdx.z;
    const int t0 = c * CHUNK;
    const int dbase = d & ~0x18;
    const int dch = (d >> 3) & 3;

    float An[D_STATE];
    bool fast = true;
    #pragma unroll
    for (int n = 0; n < D_STATE; ++n) {
        An[n] = -__expf(A_log[d * D_STATE + n]);
        fast = fast && (fabsf(An[n] + (float)(n + 1)) < 2e-3f);
    }
    const float* dt_p = dtb + ((size_t)b * SEQ + t0) * D_INNER + d;
    const unsigned short* xrow = xconv + ((size_t)b * SEQ + t0) * D_INNER;
    const float* Brow = dbl + ((size_t)b * SEQ + t0) * DBL_N + DT_RANK;   // wave-uniform

    float h[D_STATE];
    #pragma unroll
    for (int n = 0; n < D_STATE; ++n) h[n] = 0.f;
    float sumdt = 0.f;

    if (fast) {
        for (int t = 0; t < CHUNK; ++t) {
            float dt = dt_p[(size_t)t * D_INNER];
            int xcol = dbase | (((dch ^ (t >> 1)) & 3) << 3);
            float xv = bf2f(xrow[(size_t)t * D_INNER + xcol]);
            const float4* B4 = (const float4*)(Brow + (size_t)t * DBL_N);
            float4 b0 = B4[0], b1 = B4[1], b2 = B4[2], b3 = B4[3];
            float Bv[16] = {b0.x,b0.y,b0.z,b0.w, b1.x,b1.y,b1.z,b1.w,
                            b2.x,b2.y,b2.z,b2.w, b3.x,b3.y,b3.z,b3.w};
            sumdt += dt;
            float e1 = __expf(-dt);
            float dtx = dt * xv;
            float ea = 1.f;
            #pragma unroll
            for (int n = 0; n < D_STATE; ++n) {
                ea *= e1;
                h[n] = fmaf(h[n], ea, dtx * Bv[n]);
            }
        }
    } else {
        for (int t = 0; t < CHUNK; ++t) {
            float dt = dt_p[(size_t)t * D_INNER];
            int xcol = dbase | (((dch ^ (t >> 1)) & 3) << 3);
            float xv = bf2f(xrow[(size_t)t * D_INNER + xcol]);
            const float4* B4 = (const float4*)(Brow + (size_t)t * DBL_N);
            float4 b0 = B4[0], b1 = B4[1], b2 = B4[2], b3 = B4[3];
            float Bv[16] = {b0.x,b0.y,b0.z,b0.w, b1.x,b1.y,b1.z,b1.w,
                            b2.x,b2.y,b2.z,b2.w, b3.x,b3.y,b3.z,b3.w};
            sumdt += dt;
            float dtx = dt * xv;
            #pragma unroll
            for (int n = 0; n < D_STATE; ++n) {
                float ea = __expf(dt * An[n]);
                h[n] = fmaf(h[n], ea, dtx * Bv[n]);
            }
        }
    }

    float a[D_STATE];
    if (fast) {
        float E = __expf(-sumdt);
        float ea = 1.f;
        #pragma unroll
        for (int n = 0; n < D_STATE; ++n) { ea *= E; a[n] = ea; }
    } else {
        #pragma unroll
        for (int n = 0; n < D_STATE; ++n) a[n] = __expf(An[n] * sumdt);
    }
    size_t base = (((size_t)b * D_INNER + d) * NCHUNK + c) * D_STATE;
    #pragma unroll
    for (int i = 0; i < 4; ++i) {
        ((float4*)(sum_a + base))[i] = (float4){a[4*i], a[4*i+1], a[4*i+2], a[4*i+3]};
        ((float4*)(sum_h + base))[i] = (float4){h[4*i], h[4*i+1], h[4*i+2], h[4*i+3]};
    }
}

// ---------------- Scan phase 2: inter-chunk carry (in-place over sum_h) ----------------
__global__ __launch_bounds__(256) void scan_carry_kernel(
    const float* __restrict__ sum_a, float* __restrict__ sum_h)
{
    size_t g = (size_t)blockIdx.x * 256 + threadIdx.x;   // (b,d,n): 65536 groups
    size_t bd = g >> 4;
    int n = (int)(g & 15);
    size_t base = bd * NCHUNK * D_STATE + n;
    float hh = 0.f;
    for (int c = 0; c < NCHUNK; ++c) {
        size_t idx = base + (size_t)c * D_STATE;
        float a = sum_a[idx];
        float hp = sum_h[idx];
        sum_h[idx] = hh;
        hh = fmaf(hh, a, hp);
    }
}

// ---------------- Scan phase 3: re-scan with carry, emit y (bf16 swizzled) ----------
__global__ __launch_bounds__(256) void scan_phase3_kernel(
    const float* __restrict__ dtb, const unsigned short* __restrict__ xconv,
    const unsigned short* __restrict__ xz, const float* __restrict__ dbl,
    const float* __restrict__ A_log, const float* __restrict__ Dvec,
    const float* __restrict__ hinit, unsigned short* __restrict__ y)
{
    const int d = blockIdx.y * 256 + threadIdx.x;
    const int c = blockIdx.x;
    const int b = blockIdx.z;
    const int t0 = c * CHUNK;
    const int dbase = d & ~0x18;
    const int dch = (d >> 3) & 3;

    float An[D_STATE];
    bool fast = true;
    #pragma unroll
    for (int n = 0; n < D_STATE; ++n) {
        An[n] = -__expf(A_log[d * D_STATE + n]);
        fast = fast && (fabsf(An[n] + (float)(n + 1)) < 2e-3f);
    }
    const float Dd = Dvec[d];
    const float* dt_p = dtb + ((size_t)b * SEQ + t0) * D_INNER + d;
    const unsigned short* xrow = xconv + ((size_t)b * SEQ + t0) * D_INNER;
    const unsigned short* z_p = xz + ((size_t)b * SEQ + t0) * (2 * D_INNER) + D_INNER + d;
    const float* Brow = dbl + ((size_t)b * SEQ + t0) * DBL_N + DT_RANK;
    unsigned short* yrow = y + ((size_t)b * SEQ + t0) * D_INNER;

    size_t base = (((size_t)b * D_INNER + d) * NCHUNK + c) * D_STATE;
    float h[D_STATE];
    #pragma unroll
    for (int i = 0; i < 4; ++i) {
        float4 hv = ((const float4*)(hinit + base))[i];
        h[4*i] = hv.x; h[4*i+1] = hv.y; h[4*i+2] = hv.z; h[4*i+3] = hv.w;
    }

    if (fast) {
        for (int t = 0; t < CHUNK; ++t) {
            float dt = dt_p[(size_t)t * D_INNER];
            int xcol = dbase | (((dch ^ (t >> 1)) & 3) << 3);
            float xv = bf2f(xrow[(size_t)t * D_INNER + xcol]);
            const float4* B4 = (const float4*)(Brow + (size_t)t * DBL_N);
            float4 b0 = B4[0], b1 = B4[1], b2 = B4[2], b3 = B4[3];
            float4 c0 = B4[4], c1 = B4[5], c2 = B4[6], c3 = B4[7];
            float Bv[16] = {b0.x,b0.y,b0.z,b0.w, b1.x,b1.y,b1.z,b1.w,
                            b2.x,b2.y,b2.z,b2.w, b3.x,b3.y,b3.z,b3.w};
            float Cv[16] = {c0.x,c0.y,c0.z,c0.w, c1.x,c1.y,c1.z,c1.w,
                            c2.x,c2.y,c2.z,c2.w, c3.x,c3.y,c3.z,c3.w};
            float e1 = __expf(-dt);
            float dtx = dt * xv;
            float ea = 1.f, yy = 0.f;
            #pragma unroll
            for (int n = 0; n < D_STATE; ++n) {
                ea *= e1;
                h[n] = fmaf(h[n], ea, dtx * Bv[n]);
                yy = fmaf(h[n], Cv[n], yy);
            }
            float zv = bf2f(z_p[(size_t)t * (2 * D_INNER)]);
            float sig = 1.0f / (1.0f + __expf(-zv));
            yrow[(size_t)t * D_INNER + xcol] = f2bf((yy + xv * Dd) * (zv * sig));
        }
    } else {
        for (int t = 0; t < CHUNK; ++t) {
            float dt = dt_p[(size_t)t * D_INNER];
            int xcol = dbase | (((dch ^ (t >> 1)) & 3) << 3);
            float xv = bf2f(xrow[(size_t)t * D_INNER + xcol]);
            const float4* B4 = (const float4*)(Brow + (size_t)t * DBL_N);
            float4 b0 = B4[0], b1 = B4[1], b2 = B4[2], b3 = B4[3];
            float4 c0 = B4[4], c1 = B4[5], c2 = B4[6], c3 = B4[7];
            float Bv[16] = {b0.x,b0.y,b0.z,b0.w, b1.x,b1.y,b1.z,b1.w,
                            b2.x,b2.y,b2.z,b2.w, b3.x,b3.y,b3.z,b3.w};
            float Cv[16] = {c0.x,c0.y,c0.z,c0.w, c1.x,c1.y,c1.z,c1.w,
                            c2.x,c2.y,c2.z,c2.w, c3.x,c3.y,c3.z,c3.w};
            float dtx = dt * xv;
            float yy = 0.f;
            #pragma unroll
            for (int n = 0; n < D_STATE; ++n) {
                float ea = __expf(dt * An[n]);
                h[n] = fmaf(h[n], ea, dtx * Bv[n]);
                yy = fmaf(h[n], Cv[n], yy);
            }
            float zv = bf2f(z_p[(size_t)t * (2 * D_INNER)]);
            float sig = 1.0f / (1.0f + __expf(-zv));
            yrow[(size_t)t * D_INNER + xcol] = f2bf((yy + xv * Dd) * (zv * sig));
        }
    }
}

extern "C" void kernel_launch(void* const* d_in, const int* in_sizes, int n_in,
                              void* d_out, int out_size, void* d_ws, size_t ws_size,
                              hipStream_t stream) {
    const float* hs        = (const float*)d_in[0];
    const float* norm_w    = (const float*)d_in[1];
    const float* in_proj_w = (const float*)d_in[2];
    const float* conv_w    = (const float*)d_in[3];
    const float* conv_b    = (const float*)d_in[4];
    const float* x_proj_w  = (const float*)d_in[5];
    const float* dt_proj_w = (const float*)d_in[6];
    const float* dt_proj_b = (const float*)d_in[7];
    const float* A_log     = (const float*)d_in[8];
    const float* Dvec      = (const float*)d_in[9];
    const float* out_proj_w= (const float*)d_in[10];
    float* out = (float*)d_out;

    float* wsf      = (float*)d_ws;
    float* dbl      = wsf;                                //   393,216 f
    float* dbl_part = dbl      + (size_t)393216;          // 1,572,864 f
    float* dtb      = dbl_part + (size_t)1572864;         // 8,388,608 f
    float* sum_a    = dtb      + (size_t)8388608;         // 2,097,152 f
    float* sum_h    = sum_a    + (size_t)2097152;         // 2,097,152 f
    unsigned short* xz_bf    = (unsigned short*)(sum_h + 2097152); // 16,777,216 us
    unsigned short* xconv_bf = xz_bf    + (size_t)16777216;        //  8,388,608 us
    unsigned short* hnorm_bf = xconv_bf + (size_t)8388608;         //  4,194,304 us
    unsigned short* ybuf_bf  = hnorm_bf + (size_t)4194304;         //  8,388,608 us
    unsigned short* wi_bf    = ybuf_bf  + (size_t)8388608;         //  4,194,304 us
    unsigned short* wo_bf    = wi_bf    + (size_t)4194304;         //  2,097,152 us
    unsigned short* wx_bf    = wo_bf    + (size_t)2097152;         //    262,144 us (128-row pad)
    unsigned short* wdt_bf   = wx_bf    + (size_t)262144;          //    131,072 us
    unsigned short* dtr_bf   = wdt_bf   + (size_t)131072;          //    262,144 us

    // fused swizzled weight casts: wi(1024/row), wo(2048/row), wx(2048/row), wdt(64/row)
    {
        int n0 = 2 * D_INNER * D_MODEL / 4;   // wi
        int n1 = D_MODEL * D_INNER / 4;       // wo
        int n2 = DBL_N * D_INNER / 4;         // wx
        int n3 = D_INNER * DT_RANK / 4;       // wdt
        int tot = n0 + n1 + n2 + n3;
        cast4_swz_kernel<<<(tot + 255) / 256, 256, 0, stream>>>(
            (const float4*)in_proj_w,  wi_bf,  n0, 10,
            (const float4*)out_proj_w, wo_bf,  n1, 11,
            (const float4*)x_proj_w,   wx_bf,  n2, 11,
            (const float4*)dt_proj_w,  wdt_bf, n3, 6);
    }

    // 1. RMSNorm -> bf16 (swizzled)
    rmsnorm_kernel<<<NTOK, 256, 0, stream>>>(hs, norm_w, hnorm_bf);
    // 2. in_proj (MFMA): xz_bf = hnorm @ in_proj_w^T  (bf16 linear out)
    mfma_gemm_kernel<<<dim3((2 * D_INNER) / 128, NTOK / 128), 256, 0, stream>>>(
        hnorm_bf, D_MODEL, wi_bf, D_MODEL, nullptr, 0, xz_bf, 2 * D_INNER,
        D_MODEL, 2 * D_INNER, nullptr, nullptr, 0, 0, 0);
    // 3. depthwise causal conv + SiLU (bf16 in, swizzled bf16 out)
    conv_silu_kernel<<<(NTOK * D_INNER) / 256, 256, 0, stream>>>(
        xz_bf, conv_w, conv_b, xconv_bf);
    // 4. x_proj (MFMA, split-K x4): dbl_part[seg] = xconv @ x_proj_w^T (N=96)
    mfma_gemm_kernel<<<dim3(1, NTOK / 128, 4), 256, 0, stream>>>(
        xconv_bf, D_INNER, wx_bf, D_INNER, dbl_part, DBL_N, nullptr, 0,
        D_INNER / 4, DBL_N, nullptr, nullptr, 0, 0, (size_t)NTOK * DBL_N);
    reduce_xproj_kernel<<<(NTOK * DBL_N + 255) / 256, 256, 0, stream>>>(
        dbl_part, dbl, dtr_bf);
    // 5. dt_proj (MFMA) + bias + softplus -> dtb (fp32)
    mfma_gemm_kernel<<<dim3(D_INNER / 128, NTOK / 128), 256, 0, stream>>>(
        dtr_bf, DT_RANK, wdt_bf, DT_RANK, dtb, D_INNER, nullptr, 0,
        DT_RANK, D_INNER, dt_proj_b, nullptr, 0, 1, 0);
    // 6. scan: phase1 -> carry -> phase3
    scan_phase1_kernel<<<dim3(NCHUNK, D_INNER / 256, B_SZ), 256, 0, stream>>>(
        dtb, xconv_bf, dbl, A_log, sum_a, sum_h);
    scan_carry_kernel<<<(B_SZ * D_INNER * D_STATE) / 256, 256, 0, stream>>>(sum_a, sum_h);
    scan_phase3_kernel<<<dim3(NCHUNK, D_INNER / 256, B_SZ), 256, 0, stream>>>(
        dtb, xconv_bf, xz_bf, dbl, A_log, Dvec, sum_h, ybuf_bf);
    // 7. out_proj (MFMA) + residual -> d_out
    mfma_gemm_kernel<<<dim3(D_MODEL / 128, NTOK / 128), 256, 0, stream>>>(
        ybuf_bf, D_INNER, wo_bf, D_INNER, out, D_MODEL, nullptr, 0,
        D_INNER, D_MODEL, nullptr, hs, D_MODEL, 0, 0);
}

// Round 8
// 376.579 us; speedup vs baseline: 8.1662x; 1.0640x over previous
//
#include <hip/hip_runtime.h>
#include <math.h>

#define D_MODEL 1024
#define D_INNER 2048
#define D_STATE 16
#define D_CONV  4
#define DT_RANK 64
#define B_SZ    2
#define SEQ     2048
#define NTOK    (B_SZ*SEQ)            // 4096
#define DBL_N   (DT_RANK + 2*D_STATE) // 96
#define CHUNK   64
#define NCHUNK  (SEQ/CHUNK)           // 32

typedef __attribute__((ext_vector_type(8))) short short8;
typedef __attribute__((ext_vector_type(4))) float f32x4;

__device__ __forceinline__ unsigned short f2bf(float f) {
    union { float f; unsigned int u; } v; v.f = f;
    unsigned int r = v.u + 0x7fff + ((v.u >> 16) & 1);   // RNE
    return (unsigned short)(r >> 16);
}
__device__ __forceinline__ float bf2f(unsigned short u) {
    union { unsigned int u; float f; } v; v.u = ((unsigned int)u) << 16;
    return v.f;
}

// ---------------- RMSNorm: one block per token, bf16 output ----------------
__global__ __launch_bounds__(256) void rmsnorm_kernel(
    const float* __restrict__ h, const float* __restrict__ w, unsigned short* __restrict__ out)
{
    int tok = blockIdx.x;
    const float4* row = (const float4*)(h + (size_t)tok * D_MODEL);
    float4 v = row[threadIdx.x];
    float ss = v.x*v.x + v.y*v.y + v.z*v.z + v.w*v.w;
    #pragma unroll
    for (int off = 32; off >= 1; off >>= 1) ss += __shfl_down(ss, off, 64);
    __shared__ float red[4];
    int wave = threadIdx.x >> 6, lane = threadIdx.x & 63;
    if (lane == 0) red[wave] = ss;
    __syncthreads();
    float tot = red[0] + red[1] + red[2] + red[3];
    float scale = rsqrtf(tot * (1.0f / D_MODEL) + 1e-5f);
    float4 wv = ((const float4*)w)[threadIdx.x];
    ushort4 o;
    o.x = f2bf(v.x * scale * wv.x);
    o.y = f2bf(v.y * scale * wv.y);
    o.z = f2bf(v.z * scale * wv.z);
    o.w = f2bf(v.w * scale * wv.w);
    ((ushort4*)(out + (size_t)tok * D_MODEL))[threadIdx.x] = o;
}

// ---------------- fused fp32 -> bf16 cast for 4 weight matrices ----------------
__global__ __launch_bounds__(256) void cast4_kernel(
    const float4* __restrict__ s0, ushort4* __restrict__ d0, int n0,
    const float4* __restrict__ s1, ushort4* __restrict__ d1, int n1,
    const float4* __restrict__ s2, ushort4* __restrict__ d2, int n2,
    const float4* __restrict__ s3, ushort4* __restrict__ d3, int n3)
{
    int i = blockIdx.x * 256 + threadIdx.x;
    const float4* s; ushort4* d;
    if (i < n0) { s = s0; d = d0; }
    else if ((i -= n0) < n1) { s = s1; d = d1; }
    else if ((i -= n1) < n2) { s = s2; d = d2; }
    else if ((i -= n2) < n3) { s = s3; d = d3; }
    else return;
    float4 v = s[i];
    ushort4 o; o.x = f2bf(v.x); o.y = f2bf(v.y); o.z = f2bf(v.z); o.w = f2bf(v.w);
    d[i] = o;
}

// ---------------- bf16 MFMA GEMM, transposed accumulator for packed stores ----------
// acc[i][j] = mfma(Wfrag[j], Afrag[i]): lane holds C rows 16i+frow, cols 16j+quad*4+r.
// -> 4 consecutive output columns per lane: bf16 out = 8B store, fp32 out = 16B store,
//    bias / residual-add as float4 vector accesses.
__global__ __launch_bounds__(256) void mfma_gemm_kernel(
    const unsigned short* __restrict__ A, int lda,
    const unsigned short* __restrict__ W, int ldw,
    float* __restrict__ C, int ldc,
    unsigned short* __restrict__ Cbf, int ldcbf,
    int kLen, int Nmax,
    const float* __restrict__ bias,
    const float* __restrict__ add, int ldadd,
    int act, size_t segStride)
{
    __shared__ __align__(16) unsigned short As[128 * 32];
    __shared__ __align__(16) unsigned short Bs[128 * 32];
    const int bm = blockIdx.y * 128;
    const int bn = blockIdx.x * 128;
    const int kBeg = blockIdx.z * kLen;
    const int tid = threadIdx.x;
    const int lane = tid & 63;
    const int wave = tid >> 6;
    const int wm = (wave >> 1) * 64;
    const int wn = (wave & 1) * 64;
    const int frow = lane & 15;
    const int quad = lane >> 4;

    if (C) C += blockIdx.z * segStride;

    f32x4 acc[4][4];
    #pragma unroll
    for (int i = 0; i < 4; ++i)
        #pragma unroll
        for (int j = 0; j < 4; ++j)
            acc[i][j] = (f32x4){0.f, 0.f, 0.f, 0.f};

    for (int k0 = kBeg; k0 < kBeg + kLen; k0 += 32) {
        __syncthreads();
        #pragma unroll
        for (int i = 0; i < 2; ++i) {
            int q = (wave * 2 + i) * 64 + lane;
            int r = q >> 2, cl = q & 3;
            const unsigned short* ga = A + (size_t)(bm + r) * lda + k0 + cl * 8;
            const unsigned short* gb = W + (size_t)(bn + r) * ldw + k0 + cl * 8;
            __builtin_amdgcn_global_load_lds(
                (const __attribute__((address_space(1))) void*)ga,
                (__attribute__((address_space(3))) void*)(As + (wave * 2 + i) * 512),
                16, 0, 0);
            __builtin_amdgcn_global_load_lds(
                (const __attribute__((address_space(1))) void*)gb,
                (__attribute__((address_space(3))) void*)(Bs + (wave * 2 + i) * 512),
                16, 0, 0);
        }
        __syncthreads();
        short8 af[4], bf[4];
        #pragma unroll
        for (int i = 0; i < 4; ++i)
            af[i] = *(const short8*)&As[(wm + i * 16 + frow) * 32 + quad * 8];
        #pragma unroll
        for (int j = 0; j < 4; ++j)
            bf[j] = *(const short8*)&Bs[(wn + j * 16 + frow) * 32 + quad * 8];
        // swapped operands -> transposed C/D fragment (A/B operand lane layouts match)
        #pragma unroll
        for (int i = 0; i < 4; ++i)
            #pragma unroll
            for (int j = 0; j < 4; ++j)
                acc[i][j] = __builtin_amdgcn_mfma_f32_16x16x32_bf16(
                    bf[j], af[i], acc[i][j], 0, 0, 0);
    }

    // epilogue: lane -> row = bm+wm+16i+frow, cols = bn+wn+16j+quad*4 + {0..3}
    #pragma unroll
    for (int i = 0; i < 4; ++i) {
        int row = bm + wm + i * 16 + frow;
        #pragma unroll
        for (int j = 0; j < 4; ++j) {
            int col = bn + wn + j * 16 + quad * 4;
            if (col < Nmax) {
                f32x4 v = acc[i][j];
                if (bias) {
                    float4 bv = *(const float4*)&bias[col];
                    v[0] += bv.x; v[1] += bv.y; v[2] += bv.z; v[3] += bv.w;
                }
                if (act == 1) {
                    #pragma unroll
                    for (int r = 0; r < 4; ++r)
                        v[r] = (v[r] > 20.0f) ? v[r] : log1pf(__expf(v[r]));
                }
                if (add) {
                    float4 av = *(const float4*)&add[(size_t)row * ldadd + col];
                    v[0] += av.x; v[1] += av.y; v[2] += av.z; v[3] += av.w;
                }
                if (C) {
                    float4 o = {v[0], v[1], v[2], v[3]};
                    *(float4*)&C[(size_t)row * ldc + col] = o;
                }
                if (Cbf) {
                    ushort4 o = {f2bf(v[0]), f2bf(v[1]), f2bf(v[2]), f2bf(v[3])};
                    *(ushort4*)&Cbf[(size_t)row * ldcbf + col] = o;
                }
            }
        }
    }
}

// ---------------- x_proj split-K reduce + dt_r bf16 extract ----------------
__global__ __launch_bounds__(256) void reduce_xproj_kernel(
    const float* __restrict__ part, float* __restrict__ dbl,
    unsigned short* __restrict__ dtr)
{
    const int N = NTOK * DBL_N;
    int idx = blockIdx.x * 256 + threadIdx.x;
    if (idx >= N) return;
    float s = part[idx] + part[idx + N] + part[idx + 2 * N] + part[idx + 3 * N];
    dbl[idx] = s;
    unsigned int col = (unsigned int)idx % DBL_N;
    if (col < DT_RANK) {
        unsigned int tok = (unsigned int)idx / DBL_N;
        dtr[(size_t)tok * DT_RANK + col] = f2bf(s);
    }
}

// ---------------- Causal depthwise conv (k=4) + SiLU, bf16 in/out ----------------
__global__ __launch_bounds__(256) void conv_silu_kernel(
    const unsigned short* __restrict__ xz, const float* __restrict__ cw,
    const float* __restrict__ cb, unsigned short* __restrict__ out_bf)
{
    int idx = blockIdx.x * 256 + threadIdx.x;   // over NTOK*D_INNER
    int d = idx & (D_INNER - 1);
    int t = (idx >> 11) & (SEQ - 1);
    int b = idx >> 22;
    const unsigned short* xcol = xz + (size_t)b * SEQ * (2 * D_INNER) + d;
    float w0 = cw[d * 4 + 0], w1 = cw[d * 4 + 1], w2 = cw[d * 4 + 2], w3 = cw[d * 4 + 3];
    float acc = cb[d];
    if (t >= 3) acc = fmaf(bf2f(xcol[(size_t)(t - 3) * (2 * D_INNER)]), w0, acc);
    if (t >= 2) acc = fmaf(bf2f(xcol[(size_t)(t - 2) * (2 * D_INNER)]), w1, acc);
    if (t >= 1) acc = fmaf(bf2f(xcol[(size_t)(t - 1) * (2 * D_INNER)]), w2, acc);
    acc = fmaf(bf2f(xcol[(size_t)t * (2 * D_INNER)]), w3, acc);
    float sig = 1.0f / (1.0f + __expf(-acc));
    out_bf[(size_t)(b * SEQ + t) * D_INNER + d] = f2bf(acc * sig);
}

// ---------------- Scan phase 1: per-chunk summaries, one thread per d ----------------
__global__ __launch_bounds__(256) void scan_phase1_kernel(
    const float* __restrict__ dtb, const unsigned short* __restrict__ xconv,
    const float* __restrict__ dbl, const float* __restrict__ A_log,
    float* __restrict__ sum_a, float* __restrict__ sum_h)
{
    const int d = blockIdx.y * 256 + threadIdx.x;
    const int c = blockIdx.x;
    const int b = blockIdx.z;
    const int t0 = c * CHUNK;

    float An[D_STATE];
    bool fast = true;
    #pragma unroll
    for (int n = 0; n < D_STATE; ++n) {
        An[n] = -__expf(A_log[d * D_STATE + n]);
        fast = fast && (fabsf(An[n] + (float)(n + 1)) < 2e-3f);
    }
    const float* dt_p = dtb + ((size_t)b * SEQ + t0) * D_INNER + d;
    const unsigned short* x_p = xconv + ((size_t)b * SEQ + t0) * D_INNER + d;
    const float* Brow = dbl + ((size_t)b * SEQ + t0) * DBL_N + DT_RANK;   // wave-uniform

    float h[D_STATE];
    #pragma unroll
    for (int n = 0; n < D_STATE; ++n) h[n] = 0.f;
    float sumdt = 0.f;

    if (fast) {
        for (int t = 0; t < CHUNK; ++t) {
            float dt = dt_p[(size_t)t * D_INNER];
            float xv = bf2f(x_p[(size_t)t * D_INNER]);
            const float4* B4 = (const float4*)(Brow + (size_t)t * DBL_N);
            float4 b0 = B4[0], b1 = B4[1], b2 = B4[2], b3 = B4[3];
            float Bv[16] = {b0.x,b0.y,b0.z,b0.w, b1.x,b1.y,b1.z,b1.w,
                            b2.x,b2.y,b2.z,b2.w, b3.x,b3.y,b3.z,b3.w};
            sumdt += dt;
            float e1 = __expf(-dt);
            float dtx = dt * xv;
            float ea = 1.f;
            #pragma unroll
            for (int n = 0; n < D_STATE; ++n) {
                ea *= e1;
                h[n] = fmaf(h[n], ea, dtx * Bv[n]);
            }
        }
    } else {
        for (int t = 0; t < CHUNK; ++t) {
            float dt = dt_p[(size_t)t * D_INNER];
            float xv = bf2f(x_p[(size_t)t * D_INNER]);
            const float4* B4 = (const float4*)(Brow + (size_t)t * DBL_N);
            float4 b0 = B4[0], b1 = B4[1], b2 = B4[2], b3 = B4[3];
            float Bv[16] = {b0.x,b0.y,b0.z,b0.w, b1.x,b1.y,b1.z,b1.w,
                            b2.x,b2.y,b2.z,b2.w, b3.x,b3.y,b3.z,b3.w};
            sumdt += dt;
            float dtx = dt * xv;
            #pragma unroll
            for (int n = 0; n < D_STATE; ++n) {
                float ea = __expf(dt * An[n]);
                h[n] = fmaf(h[n], ea, dtx * Bv[n]);
            }
        }
    }

    float a[D_STATE];
    if (fast) {
        float E = __expf(-sumdt);
        float ea = 1.f;
        #pragma unroll
        for (int n = 0; n < D_STATE; ++n) { ea *= E; a[n] = ea; }
    } else {
        #pragma unroll
        for (int n = 0; n < D_STATE; ++n) a[n] = __expf(An[n] * sumdt);
    }
    size_t base = (((size_t)b * D_INNER + d) * NCHUNK + c) * D_STATE;
    #pragma unroll
    for (int i = 0; i < 4; ++i) {
        ((float4*)(sum_a + base))[i] = (float4){a[4*i], a[4*i+1], a[4*i+2], a[4*i+3]};
        ((float4*)(sum_h + base))[i] = (float4){h[4*i], h[4*i+1], h[4*i+2], h[4*i+3]};
    }
}

// ---------------- Scan phase 2: inter-chunk carry (in-place over sum_h) ----------------
__global__ __launch_bounds__(256) void scan_carry_kernel(
    const float* __restrict__ sum_a, float* __restrict__ sum_h)
{
    size_t g = (size_t)blockIdx.x * 256 + threadIdx.x;   // (b,d,n): 65536 groups
    size_t bd = g >> 4;
    int n = (int)(g & 15);
    size_t base = bd * NCHUNK * D_STATE + n;
    float hh = 0.f;
    for (int c = 0; c < NCHUNK; ++c) {
        size_t idx = base + (size_t)c * D_STATE;
        float a = sum_a[idx];
        float hp = sum_h[idx];
        sum_h[idx] = hh;
        hh = fmaf(hh, a, hp);
    }
}

// ---------------- Scan phase 3: re-scan with carry, emit y (bf16) ----------------
__global__ __launch_bounds__(256) void scan_phase3_kernel(
    const float* __restrict__ dtb, const unsigned short* __restrict__ xconv,
    const unsigned short* __restrict__ xz, const float* __restrict__ dbl,
    const float* __restrict__ A_log, const float* __restrict__ Dvec,
    const float* __restrict__ hinit, unsigned short* __restrict__ y)
{
    const int d = blockIdx.y * 256 + threadIdx.x;
    const int c = blockIdx.x;
    const int b = blockIdx.z;
    const int t0 = c * CHUNK;

    float An[D_STATE];
    bool fast = true;
    #pragma unroll
    for (int n = 0; n < D_STATE; ++n) {
        An[n] = -__expf(A_log[d * D_STATE + n]);
        fast = fast && (fabsf(An[n] + (float)(n + 1)) < 2e-3f);
    }
    const float Dd = Dvec[d];
    const float* dt_p = dtb + ((size_t)b * SEQ + t0) * D_INNER + d;
    const unsigned short* x_p = xconv + ((size_t)b * SEQ + t0) * D_INNER + d;
    const unsigned short* z_p = xz + ((size_t)b * SEQ + t0) * (2 * D_INNER) + D_INNER + d;
    const float* Brow = dbl + ((size_t)b * SEQ + t0) * DBL_N + DT_RANK;
    unsigned short* y_p = y + ((size_t)b * SEQ + t0) * D_INNER + d;

    size_t base = (((size_t)b * D_INNER + d) * NCHUNK + c) * D_STATE;
    float h[D_STATE];
    #pragma unroll
    for (int i = 0; i < 4; ++i) {
        float4 hv = ((const float4*)(hinit + base))[i];
        h[4*i] = hv.x; h[4*i+1] = hv.y; h[4*i+2] = hv.z; h[4*i+3] = hv.w;
    }

    if (fast) {
        for (int t = 0; t < CHUNK; ++t) {
            float dt = dt_p[(size_t)t * D_INNER];
            float xv = bf2f(x_p[(size_t)t * D_INNER]);
            const float4* B4 = (const float4*)(Brow + (size_t)t * DBL_N);
            float4 b0 = B4[0], b1 = B4[1], b2 = B4[2], b3 = B4[3];
            float4 c0 = B4[4], c1 = B4[5], c2 = B4[6], c3 = B4[7];
            float Bv[16] = {b0.x,b0.y,b0.z,b0.w, b1.x,b1.y,b1.z,b1.w,
                            b2.x,b2.y,b2.z,b2.w, b3.x,b3.y,b3.z,b3.w};
            float Cv[16] = {c0.x,c0.y,c0.z,c0.w, c1.x,c1.y,c1.z,c1.w,
                            c2.x,c2.y,c2.z,c2.w, c3.x,c3.y,c3.z,c3.w};
            float e1 = __expf(-dt);
            float dtx = dt * xv;
            float ea = 1.f, yy = 0.f;
            #pragma unroll
            for (int n = 0; n < D_STATE; ++n) {
                ea *= e1;
                h[n] = fmaf(h[n], ea, dtx * Bv[n]);
                yy = fmaf(h[n], Cv[n], yy);
            }
            float zv = bf2f(z_p[(size_t)t * (2 * D_INNER)]);
            float sig = 1.0f / (1.0f + __expf(-zv));
            y_p[(size_t)t * D_INNER] = f2bf((yy + xv * Dd) * (zv * sig));
        }
    } else {
        for (int t = 0; t < CHUNK; ++t) {
            float dt = dt_p[(size_t)t * D_INNER];
            float xv = bf2f(x_p[(size_t)t * D_INNER]);
            const float4* B4 = (const float4*)(Brow + (size_t)t * DBL_N);
            float4 b0 = B4[0], b1 = B4[1], b2 = B4[2], b3 = B4[3];
            float4 c0 = B4[4], c1 = B4[5], c2 = B4[6], c3 = B4[7];
            float Bv[16] = {b0.x,b0.y,b0.z,b0.w, b1.x,b1.y,b1.z,b1.w,
                            b2.x,b2.y,b2.z,b2.w, b3.x,b3.y,b3.z,b3.w};
            float Cv[16] = {c0.x,c0.y,c0.z,c0.w, c1.x,c1.y,c1.z,c1.w,
                            c2.x,c2.y,c2.z,c2.w, c3.x,c3.y,c3.z,c3.w};
            float dtx = dt * xv;
            float yy = 0.f;
            #pragma unroll
            for (int n = 0; n < D_STATE; ++n) {
                float ea = __expf(dt * An[n]);
                h[n] = fmaf(h[n], ea, dtx * Bv[n]);
                yy = fmaf(h[n], Cv[n], yy);
            }
            float zv = bf2f(z_p[(size_t)t * (2 * D_INNER)]);
            float sig = 1.0f / (1.0f + __expf(-zv));
            y_p[(size_t)t * D_INNER] = f2bf((yy + xv * Dd) * (zv * sig));
        }
    }
}

extern "C" void kernel_launch(void* const* d_in, const int* in_sizes, int n_in,
                              void* d_out, int out_size, void* d_ws, size_t ws_size,
                              hipStream_t stream) {
    const float* hs        = (const float*)d_in[0];
    const float* norm_w    = (const float*)d_in[1];
    const float* in_proj_w = (const float*)d_in[2];
    const float* conv_w    = (const float*)d_in[3];
    const float* conv_b    = (const float*)d_in[4];
    const float* x_proj_w  = (const float*)d_in[5];
    const float* dt_proj_w = (const float*)d_in[6];
    const float* dt_proj_b = (const float*)d_in[7];
    const float* A_log     = (const float*)d_in[8];
    const float* Dvec      = (const float*)d_in[9];
    const float* out_proj_w= (const float*)d_in[10];
    float* out = (float*)d_out;

    float* wsf      = (float*)d_ws;
    float* dbl      = wsf;                                //   393,216 f
    float* dbl_part = dbl      + (size_t)393216;          // 1,572,864 f
    float* dtb      = dbl_part + (size_t)1572864;         // 8,388,608 f
    float* sum_a    = dtb      + (size_t)8388608;         // 2,097,152 f
    float* sum_h    = sum_a    + (size_t)2097152;         // 2,097,152 f
    unsigned short* xz_bf    = (unsigned short*)(sum_h + 2097152); // 16,777,216 us
    unsigned short* xconv_bf = xz_bf    + (size_t)16777216;        //  8,388,608 us
    unsigned short* hnorm_bf = xconv_bf + (size_t)8388608;         //  4,194,304 us
    unsigned short* ybuf_bf  = hnorm_bf + (size_t)4194304;         //  8,388,608 us
    unsigned short* wi_bf    = ybuf_bf  + (size_t)8388608;         //  4,194,304 us
    unsigned short* wo_bf    = wi_bf    + (size_t)4194304;         //  2,097,152 us
    unsigned short* wx_bf    = wo_bf    + (size_t)2097152;         //    262,144 us (128-row pad)
    unsigned short* wdt_bf   = wx_bf    + (size_t)262144;          //    131,072 us
    unsigned short* dtr_bf   = wdt_bf   + (size_t)131072;          //    262,144 us

    // fused weight casts
    {
        int n0 = 2 * D_INNER * D_MODEL / 4;   // wi
        int n1 = D_MODEL * D_INNER / 4;       // wo
        int n2 = DBL_N * D_INNER / 4;         // wx
        int n3 = D_INNER * DT_RANK / 4;       // wdt
        int tot = n0 + n1 + n2 + n3;
        cast4_kernel<<<(tot + 255) / 256, 256, 0, stream>>>(
            (const float4*)in_proj_w,  (ushort4*)wi_bf,  n0,
            (const float4*)out_proj_w, (ushort4*)wo_bf,  n1,
            (const float4*)x_proj_w,   (ushort4*)wx_bf,  n2,
            (const float4*)dt_proj_w,  (ushort4*)wdt_bf, n3);
    }

    // 1. RMSNorm -> bf16
    rmsnorm_kernel<<<NTOK, 256, 0, stream>>>(hs, norm_w, hnorm_bf);
    // 2. in_proj (MFMA): xz_bf = hnorm @ in_proj_w^T  (bf16 out, packed stores)
    mfma_gemm_kernel<<<dim3((2 * D_INNER) / 128, NTOK / 128), 256, 0, stream>>>(
        hnorm_bf, D_MODEL, wi_bf, D_MODEL, nullptr, 0, xz_bf, 2 * D_INNER,
        D_MODEL, 2 * D_INNER, nullptr, nullptr, 0, 0, 0);
    // 3. depthwise causal conv + SiLU (bf16 in/out)
    conv_silu_kernel<<<(NTOK * D_INNER) / 256, 256, 0, stream>>>(
        xz_bf, conv_w, conv_b, xconv_bf);
    // 4. x_proj (MFMA, split-K x4): dbl_part[seg] = xconv @ x_proj_w^T (N=96)
    mfma_gemm_kernel<<<dim3(1, NTOK / 128, 4), 256, 0, stream>>>(
        xconv_bf, D_INNER, wx_bf, D_INNER, dbl_part, DBL_N, nullptr, 0,
        D_INNER / 4, DBL_N, nullptr, nullptr, 0, 0, (size_t)NTOK * DBL_N);
    reduce_xproj_kernel<<<(NTOK * DBL_N + 255) / 256, 256, 0, stream>>>(
        dbl_part, dbl, dtr_bf);
    // 5. dt_proj (MFMA) + bias + softplus -> dtb (fp32)
    mfma_gemm_kernel<<<dim3(D_INNER / 128, NTOK / 128), 256, 0, stream>>>(
        dtr_bf, DT_RANK, wdt_bf, DT_RANK, dtb, D_INNER, nullptr, 0,
        DT_RANK, D_INNER, dt_proj_b, nullptr, 0, 1, 0);
    // 6. scan: phase1 -> carry -> phase3
    scan_phase1_kernel<<<dim3(NCHUNK, D_INNER / 256, B_SZ), 256, 0, stream>>>(
        dtb, xconv_bf, dbl, A_log, sum_a, sum_h);
    scan_carry_kernel<<<(B_SZ * D_INNER * D_STATE) / 256, 256, 0, stream>>>(sum_a, sum_h);
    scan_phase3_kernel<<<dim3(NCHUNK, D_INNER / 256, B_SZ), 256, 0, stream>>>(
        dtb, xconv_bf, xz_bf, dbl, A_log, Dvec, sum_h, ybuf_bf);
    // 7. out_proj (MFMA) + residual -> d_out (float4 stores + float4 residual loads)
    mfma_gemm_kernel<<<dim3(D_MODEL / 128, NTOK / 128), 256, 0, stream>>>(
        ybuf_bf, D_INNER, wo_bf, D_INNER, out, D_MODEL, nullptr, 0,
        D_INNER, D_MODEL, nullptr, hs, D_MODEL, 0, 0);
}

// Round 9
// 347.105 us; speedup vs baseline: 8.8596x; 1.0849x over previous
//
#include <hip/hip_runtime.h>
#include <math.h>

#define D_MODEL 1024
#define D_INNER 2048
#define D_STATE 16
#define D_CONV  4
#define DT_RANK 64
#define B_SZ    2
#define SEQ     2048
#define NTOK    (B_SZ*SEQ)            // 4096
#define DBL_N   (DT_RANK + 2*D_STATE) // 96
#define CHUNK   64
#define NCHUNK  (SEQ/CHUNK)           // 32

typedef __attribute__((ext_vector_type(8))) short short8;
typedef __attribute__((ext_vector_type(4))) float f32x4;

__device__ __forceinline__ unsigned short f2bf(float f) {
    union { float f; unsigned int u; } v; v.f = f;
    unsigned int r = v.u + 0x7fff + ((v.u >> 16) & 1);   // RNE
    return (unsigned short)(r >> 16);
}
__device__ __forceinline__ float bf2f(unsigned short u) {
    union { unsigned int u; float f; } v; v.u = ((unsigned int)u) << 16;
    return v.f;
}

// ---------------- RMSNorm: one block per token, bf16 output ----------------
__global__ __launch_bounds__(256) void rmsnorm_kernel(
    const float* __restrict__ h, const float* __restrict__ w, unsigned short* __restrict__ out)
{
    int tok = blockIdx.x;
    const float4* row = (const float4*)(h + (size_t)tok * D_MODEL);
    float4 v = row[threadIdx.x];
    float ss = v.x*v.x + v.y*v.y + v.z*v.z + v.w*v.w;
    #pragma unroll
    for (int off = 32; off >= 1; off >>= 1) ss += __shfl_down(ss, off, 64);
    __shared__ float red[4];
    int wave = threadIdx.x >> 6, lane = threadIdx.x & 63;
    if (lane == 0) red[wave] = ss;
    __syncthreads();
    float tot = red[0] + red[1] + red[2] + red[3];
    float scale = rsqrtf(tot * (1.0f / D_MODEL) + 1e-5f);
    float4 wv = ((const float4*)w)[threadIdx.x];
    ushort4 o;
    o.x = f2bf(v.x * scale * wv.x);
    o.y = f2bf(v.y * scale * wv.y);
    o.z = f2bf(v.z * scale * wv.z);
    o.w = f2bf(v.w * scale * wv.w);
    ((ushort4*)(out + (size_t)tok * D_MODEL))[threadIdx.x] = o;
}

// ---------------- fused fp32 -> bf16 cast for 4 weight matrices ----------------
__global__ __launch_bounds__(256) void cast4_kernel(
    const float4* __restrict__ s0, ushort4* __restrict__ d0, int n0,
    const float4* __restrict__ s1, ushort4* __restrict__ d1, int n1,
    const float4* __restrict__ s2, ushort4* __restrict__ d2, int n2,
    const float4* __restrict__ s3, ushort4* __restrict__ d3, int n3)
{
    int i = blockIdx.x * 256 + threadIdx.x;
    const float4* s; ushort4* d;
    if (i < n0) { s = s0; d = d0; }
    else if ((i -= n0) < n1) { s = s1; d = d1; }
    else if ((i -= n1) < n2) { s = s2; d = d2; }
    else if ((i -= n2) < n3) { s = s3; d = d3; }
    else return;
    float4 v = s[i];
    ushort4 o; o.x = f2bf(v.x); o.y = f2bf(v.y); o.z = f2bf(v.z); o.w = f2bf(v.w);
    d[i] = o;
}

// ---------------- bf16 MFMA GEMM, transposed accumulator for packed stores ----------
// acc[i][j] = mfma(Wfrag[j], Afrag[i]): lane holds C rows 16i+frow, cols 16j+quad*4+r.
__global__ __launch_bounds__(256) void mfma_gemm_kernel(
    const unsigned short* __restrict__ A, int lda,
    const unsigned short* __restrict__ W, int ldw,
    float* __restrict__ C, int ldc,
    unsigned short* __restrict__ Cbf, int ldcbf,
    int kLen, int Nmax,
    const float* __restrict__ add, int ldadd,
    size_t segStride)
{
    __shared__ __align__(16) unsigned short As[128 * 32];
    __shared__ __align__(16) unsigned short Bs[128 * 32];
    const int bm = blockIdx.y * 128;
    const int bn = blockIdx.x * 128;
    const int kBeg = blockIdx.z * kLen;
    const int tid = threadIdx.x;
    const int lane = tid & 63;
    const int wave = tid >> 6;
    const int wm = (wave >> 1) * 64;
    const int wn = (wave & 1) * 64;
    const int frow = lane & 15;
    const int quad = lane >> 4;

    if (C) C += blockIdx.z * segStride;

    f32x4 acc[4][4];
    #pragma unroll
    for (int i = 0; i < 4; ++i)
        #pragma unroll
        for (int j = 0; j < 4; ++j)
            acc[i][j] = (f32x4){0.f, 0.f, 0.f, 0.f};

    for (int k0 = kBeg; k0 < kBeg + kLen; k0 += 32) {
        __syncthreads();
        #pragma unroll
        for (int i = 0; i < 2; ++i) {
            int q = (wave * 2 + i) * 64 + lane;
            int r = q >> 2, cl = q & 3;
            const unsigned short* ga = A + (size_t)(bm + r) * lda + k0 + cl * 8;
            const unsigned short* gb = W + (size_t)(bn + r) * ldw + k0 + cl * 8;
            __builtin_amdgcn_global_load_lds(
                (const __attribute__((address_space(1))) void*)ga,
                (__attribute__((address_space(3))) void*)(As + (wave * 2 + i) * 512),
                16, 0, 0);
            __builtin_amdgcn_global_load_lds(
                (const __attribute__((address_space(1))) void*)gb,
                (__attribute__((address_space(3))) void*)(Bs + (wave * 2 + i) * 512),
                16, 0, 0);
        }
        __syncthreads();
        short8 af[4], bf[4];
        #pragma unroll
        for (int i = 0; i < 4; ++i)
            af[i] = *(const short8*)&As[(wm + i * 16 + frow) * 32 + quad * 8];
        #pragma unroll
        for (int j = 0; j < 4; ++j)
            bf[j] = *(const short8*)&Bs[(wn + j * 16 + frow) * 32 + quad * 8];
        #pragma unroll
        for (int i = 0; i < 4; ++i)
            #pragma unroll
            for (int j = 0; j < 4; ++j)
                acc[i][j] = __builtin_amdgcn_mfma_f32_16x16x32_bf16(
                    bf[j], af[i], acc[i][j], 0, 0, 0);
    }

    // epilogue: lane -> row = bm+wm+16i+frow, cols = bn+wn+16j+quad*4 + {0..3}
    #pragma unroll
    for (int i = 0; i < 4; ++i) {
        int row = bm + wm + i * 16 + frow;
        #pragma unroll
        for (int j = 0; j < 4; ++j) {
            int col = bn + wn + j * 16 + quad * 4;
            if (col < Nmax) {
                f32x4 v = acc[i][j];
                if (add) {
                    float4 av = *(const float4*)&add[(size_t)row * ldadd + col];
                    v[0] += av.x; v[1] += av.y; v[2] += av.z; v[3] += av.w;
                }
                if (C) {
                    float4 o = {v[0], v[1], v[2], v[3]};
                    *(float4*)&C[(size_t)row * ldc + col] = o;
                }
                if (Cbf) {
                    ushort4 o = {f2bf(v[0]), f2bf(v[1]), f2bf(v[2]), f2bf(v[3])};
                    *(ushort4*)&Cbf[(size_t)row * ldcbf + col] = o;
                }
            }
        }
    }
}

// ---------------- dt_proj: 64x64-tile MFMA GEMM + bias + fast softplus ----------------
// M=NTOK, N=D_INNER, K=64. 2048 blocks -> 8/CU. A: dtr (NTOK x 64), W: wdt (2048 x 64).
__global__ __launch_bounds__(256) void dtproj_kernel(
    const unsigned short* __restrict__ A,
    const unsigned short* __restrict__ W,
    const float* __restrict__ bias,
    float* __restrict__ C)
{
    __shared__ __align__(16) unsigned short As[64 * 32];
    __shared__ __align__(16) unsigned short Bs[64 * 32];
    const int bm = blockIdx.y * 64;
    const int bn = blockIdx.x * 64;
    const int tid = threadIdx.x;
    const int lane = tid & 63;
    const int wave = tid >> 6;
    const int frow = lane & 15;
    const int quad = lane >> 4;

    f32x4 acc[4];
    #pragma unroll
    for (int i = 0; i < 4; ++i) acc[i] = (f32x4){0.f, 0.f, 0.f, 0.f};

    #pragma unroll
    for (int k0 = 0; k0 < DT_RANK; k0 += 32) {
        __syncthreads();
        {
            int r = tid >> 2, cl = tid & 3;   // 64 rows x 4 chunks of 16B
            const unsigned short* ga = A + (size_t)(bm + r) * DT_RANK + k0 + cl * 8;
            const unsigned short* gb = W + (size_t)(bn + r) * DT_RANK + k0 + cl * 8;
            __builtin_amdgcn_global_load_lds(
                (const __attribute__((address_space(1))) void*)ga,
                (__attribute__((address_space(3))) void*)(As + wave * 512),
                16, 0, 0);
            __builtin_amdgcn_global_load_lds(
                (const __attribute__((address_space(1))) void*)gb,
                (__attribute__((address_space(3))) void*)(Bs + wave * 512),
                16, 0, 0);
        }
        __syncthreads();
        short8 bf = *(const short8*)&Bs[(wave * 16 + frow) * 32 + quad * 8];
        #pragma unroll
        for (int i = 0; i < 4; ++i) {
            short8 af = *(const short8*)&As[(i * 16 + frow) * 32 + quad * 8];
            acc[i] = __builtin_amdgcn_mfma_f32_16x16x32_bf16(bf, af, acc[i], 0, 0, 0);
        }
    }

    const int col = bn + wave * 16 + quad * 4;
    float4 bv = *(const float4*)&bias[col];
    #pragma unroll
    for (int i = 0; i < 4; ++i) {
        int row = bm + i * 16 + frow;
        f32x4 v = acc[i];
        v[0] += bv.x; v[1] += bv.y; v[2] += bv.z; v[3] += bv.w;
        #pragma unroll
        for (int r = 0; r < 4; ++r)
            v[r] = (v[r] > 15.0f) ? v[r] : __logf(1.0f + __expf(v[r]));
        float4 o = {v[0], v[1], v[2], v[3]};
        *(float4*)&C[(size_t)row * D_INNER + col] = o;
    }
}

// ---------------- x_proj split-K reduce + dt_r bf16 extract ----------------
__global__ __launch_bounds__(256) void reduce_xproj_kernel(
    const float* __restrict__ part, float* __restrict__ dbl,
    unsigned short* __restrict__ dtr)
{
    const int N = NTOK * DBL_N;
    int idx = blockIdx.x * 256 + threadIdx.x;
    if (idx >= N) return;
    float s = part[idx] + part[idx + N] + part[idx + 2 * N] + part[idx + 3 * N];
    dbl[idx] = s;
    unsigned int col = (unsigned int)idx % DBL_N;
    if (col < DT_RANK) {
        unsigned int tok = (unsigned int)idx / DBL_N;
        dtr[(size_t)tok * DT_RANK + col] = f2bf(s);
    }
}

// ---------------- Causal depthwise conv (k=4) + SiLU, bf16 in/out ----------------
__global__ __launch_bounds__(256) void conv_silu_kernel(
    const unsigned short* __restrict__ xz, const float* __restrict__ cw,
    const float* __restrict__ cb, unsigned short* __restrict__ out_bf)
{
    int idx = blockIdx.x * 256 + threadIdx.x;   // over NTOK*D_INNER
    int d = idx & (D_INNER - 1);
    int t = (idx >> 11) & (SEQ - 1);
    int b = idx >> 22;
    const unsigned short* xcol = xz + (size_t)b * SEQ * (2 * D_INNER) + d;
    float w0 = cw[d * 4 + 0], w1 = cw[d * 4 + 1], w2 = cw[d * 4 + 2], w3 = cw[d * 4 + 3];
    float acc = cb[d];
    if (t >= 3) acc = fmaf(bf2f(xcol[(size_t)(t - 3) * (2 * D_INNER)]), w0, acc);
    if (t >= 2) acc = fmaf(bf2f(xcol[(size_t)(t - 2) * (2 * D_INNER)]), w1, acc);
    if (t >= 1) acc = fmaf(bf2f(xcol[(size_t)(t - 1) * (2 * D_INNER)]), w2, acc);
    acc = fmaf(bf2f(xcol[(size_t)t * (2 * D_INNER)]), w3, acc);
    float sig = 1.0f / (1.0f + __expf(-acc));
    out_bf[(size_t)(b * SEQ + t) * D_INNER + d] = f2bf(acc * sig);
}

// ---------------- Scan phase 1: per-chunk summaries, one thread per d ----------------
__global__ __launch_bounds__(256) void scan_phase1_kernel(
    const float* __restrict__ dtb, const unsigned short* __restrict__ xconv,
    const float* __restrict__ dbl, const float* __restrict__ A_log,
    float* __restrict__ sum_a, float* __restrict__ sum_h)
{
    const int d = blockIdx.y * 256 + threadIdx.x;
    const int c = blockIdx.x;
    const int b = blockIdx.z;
    const int t0 = c * CHUNK;

    float An[D_STATE];
    bool fast = true;
    #pragma unroll
    for (int n = 0; n < D_STATE; ++n) {
        An[n] = -__expf(A_log[d * D_STATE + n]);
        fast = fast && (fabsf(An[n] + (float)(n + 1)) < 2e-3f);
    }
    const float* dt_p = dtb + ((size_t)b * SEQ + t0) * D_INNER + d;
    const unsigned short* x_p = xconv + ((size_t)b * SEQ + t0) * D_INNER + d;
    const float* Brow = dbl + ((size_t)b * SEQ + t0) * DBL_N + DT_RANK;   // wave-uniform

    float h[D_STATE];
    #pragma unroll
    for (int n = 0; n < D_STATE; ++n) h[n] = 0.f;
    float sumdt = 0.f;

    if (fast) {
        for (int t = 0; t < CHUNK; ++t) {
            float dt = dt_p[(size_t)t * D_INNER];
            float xv = bf2f(x_p[(size_t)t * D_INNER]);
            const float4* B4 = (const float4*)(Brow + (size_t)t * DBL_N);
            float4 b0 = B4[0], b1 = B4[1], b2 = B4[2], b3 = B4[3];
            float Bv[16] = {b0.x,b0.y,b0.z,b0.w, b1.x,b1.y,b1.z,b1.w,
                            b2.x,b2.y,b2.z,b2.w, b3.x,b3.y,b3.z,b3.w};
            sumdt += dt;
            float e1 = __expf(-dt);
            float dtx = dt * xv;
            float ea = 1.f;
            #pragma unroll
            for (int n = 0; n < D_STATE; ++n) {
                ea *= e1;
                h[n] = fmaf(h[n], ea, dtx * Bv[n]);
            }
        }
    } else {
        for (int t = 0; t < CHUNK; ++t) {
            float dt = dt_p[(size_t)t * D_INNER];
            float xv = bf2f(x_p[(size_t)t * D_INNER]);
            const float4* B4 = (const float4*)(Brow + (size_t)t * DBL_N);
            float4 b0 = B4[0], b1 = B4[1], b2 = B4[2], b3 = B4[3];
            float Bv[16] = {b0.x,b0.y,b0.z,b0.w, b1.x,b1.y,b1.z,b1.w,
                            b2.x,b2.y,b2.z,b2.w, b3.x,b3.y,b3.z,b3.w};
            sumdt += dt;
            float dtx = dt * xv;
            #pragma unroll
            for (int n = 0; n < D_STATE; ++n) {
                float ea = __expf(dt * An[n]);
                h[n] = fmaf(h[n], ea, dtx * Bv[n]);
            }
        }
    }

    float a[D_STATE];
    if (fast) {
        float E = __expf(-sumdt);
        float ea = 1.f;
        #pragma unroll
        for (int n = 0; n < D_STATE; ++n) { ea *= E; a[n] = ea; }
    } else {
        #pragma unroll
        for (int n = 0; n < D_STATE; ++n) a[n] = __expf(An[n] * sumdt);
    }
    size_t base = (((size_t)b * D_INNER + d) * NCHUNK + c) * D_STATE;
    #pragma unroll
    for (int i = 0; i < 4; ++i) {
        ((float4*)(sum_a + base))[i] = (float4){a[4*i], a[4*i+1], a[4*i+2], a[4*i+3]};
        ((float4*)(sum_h + base))[i] = (float4){h[4*i], h[4*i+1], h[4*i+2], h[4*i+3]};
    }
}

// ---------------- Scan phase 2: inter-chunk carry (in-place over sum_h) ----------------
__global__ __launch_bounds__(256) void scan_carry_kernel(
    const float* __restrict__ sum_a, float* __restrict__ sum_h)
{
    size_t g = (size_t)blockIdx.x * 256 + threadIdx.x;   // (b,d,n): 65536 groups
    size_t bd = g >> 4;
    int n = (int)(g & 15);
    size_t base = bd * NCHUNK * D_STATE + n;
    float hh = 0.f;
    for (int c = 0; c < NCHUNK; ++c) {
        size_t idx = base + (size_t)c * D_STATE;
        float a = sum_a[idx];
        float hp = sum_h[idx];
        sum_h[idx] = hh;
        hh = fmaf(hh, a, hp);
    }
}

// ---------------- Scan phase 3: re-scan with carry, emit y (bf16) ----------------
__global__ __launch_bounds__(256) void scan_phase3_kernel(
    const float* __restrict__ dtb, const unsigned short* __restrict__ xconv,
    const unsigned short* __restrict__ xz, const float* __restrict__ dbl,
    const float* __restrict__ A_log, const float* __restrict__ Dvec,
    const float* __restrict__ hinit, unsigned short* __restrict__ y)
{
    const int d = blockIdx.y * 256 + threadIdx.x;
    const int c = blockIdx.x;
    const int b = blockIdx.z;
    const int t0 = c * CHUNK;

    float An[D_STATE];
    bool fast = true;
    #pragma unroll
    for (int n = 0; n < D_STATE; ++n) {
        An[n] = -__expf(A_log[d * D_STATE + n]);
        fast = fast && (fabsf(An[n] + (float)(n + 1)) < 2e-3f);
    }
    const float Dd = Dvec[d];
    const float* dt_p = dtb + ((size_t)b * SEQ + t0) * D_INNER + d;
    const unsigned short* x_p = xconv + ((size_t)b * SEQ + t0) * D_INNER + d;
    const unsigned short* z_p = xz + ((size_t)b * SEQ + t0) * (2 * D_INNER) + D_INNER + d;
    const float* Brow = dbl + ((size_t)b * SEQ + t0) * DBL_N + DT_RANK;
    unsigned short* y_p = y + ((size_t)b * SEQ + t0) * D_INNER + d;

    size_t base = (((size_t)b * D_INNER + d) * NCHUNK + c) * D_STATE;
    float h[D_STATE];
    #pragma unroll
    for (int i = 0; i < 4; ++i) {
        float4 hv = ((const float4*)(hinit + base))[i];
        h[4*i] = hv.x; h[4*i+1] = hv.y; h[4*i+2] = hv.z; h[4*i+3] = hv.w;
    }

    if (fast) {
        for (int t = 0; t < CHUNK; ++t) {
            float dt = dt_p[(size_t)t * D_INNER];
            float xv = bf2f(x_p[(size_t)t * D_INNER]);
            const float4* B4 = (const float4*)(Brow + (size_t)t * DBL_N);
            float4 b0 = B4[0], b1 = B4[1], b2 = B4[2], b3 = B4[3];
            float4 c0 = B4[4], c1 = B4[5], c2 = B4[6], c3 = B4[7];
            float Bv[16] = {b0.x,b0.y,b0.z,b0.w, b1.x,b1.y,b1.z,b1.w,
                            b2.x,b2.y,b2.z,b2.w, b3.x,b3.y,b3.z,b3.w};
            float Cv[16] = {c0.x,c0.y,c0.z,c0.w, c1.x,c1.y,c1.z,c1.w,
                            c2.x,c2.y,c2.z,c2.w, c3.x,c3.y,c3.z,c3.w};
            float e1 = __expf(-dt);
            float dtx = dt * xv;
            float ea = 1.f, yy = 0.f;
            #pragma unroll
            for (int n = 0; n < D_STATE; ++n) {
                ea *= e1;
                h[n] = fmaf(h[n], ea, dtx * Bv[n]);
                yy = fmaf(h[n], Cv[n], yy);
            }
            float zv = bf2f(z_p[(size_t)t * (2 * D_INNER)]);
            float sig = 1.0f / (1.0f + __expf(-zv));
            y_p[(size_t)t * D_INNER] = f2bf((yy + xv * Dd) * (zv * sig));
        }
    } else {
        for (int t = 0; t < CHUNK; ++t) {
            float dt = dt_p[(size_t)t * D_INNER];
            float xv = bf2f(x_p[(size_t)t * D_INNER]);
            const float4* B4 = (const float4*)(Brow + (size_t)t * DBL_N);
            float4 b0 = B4[0], b1 = B4[1], b2 = B4[2], b3 = B4[3];
            float4 c0 = B4[4], c1 = B4[5], c2 = B4[6], c3 = B4[7];
            float Bv[16] = {b0.x,b0.y,b0.z,b0.w, b1.x,b1.y,b1.z,b1.w,
                            b2.x,b2.y,b2.z,b2.w, b3.x,b3.y,b3.z,b3.w};
            float Cv[16] = {c0.x,c0.y,c0.z,c0.w, c1.x,c1.y,c1.z,c1.w,
                            c2.x,c2.y,c2.z,c2.w, c3.x,c3.y,c3.z,c3.w};
            float dtx = dt * xv;
            float yy = 0.f;
            #pragma unroll
            for (int n = 0; n < D_STATE; ++n) {
                float ea = __expf(dt * An[n]);
                h[n] = fmaf(h[n], ea, dtx * Bv[n]);
                yy = fmaf(h[n], Cv[n], yy);
            }
            float zv = bf2f(z_p[(size_t)t * (2 * D_INNER)]);
            float sig = 1.0f / (1.0f + __expf(-zv));
            y_p[(size_t)t * D_INNER] = f2bf((yy + xv * Dd) * (zv * sig));
        }
    }
}

extern "C" void kernel_launch(void* const* d_in, const int* in_sizes, int n_in,
                              void* d_out, int out_size, void* d_ws, size_t ws_size,
                              hipStream_t stream) {
    const float* hs        = (const float*)d_in[0];
    const float* norm_w    = (const float*)d_in[1];
    const float* in_proj_w = (const float*)d_in[2];
    const float* conv_w    = (const float*)d_in[3];
    const float* conv_b    = (const float*)d_in[4];
    const float* x_proj_w  = (const float*)d_in[5];
    const float* dt_proj_w = (const float*)d_in[6];
    const float* dt_proj_b = (const float*)d_in[7];
    const float* A_log     = (const float*)d_in[8];
    const float* Dvec      = (const float*)d_in[9];
    const float* out_proj_w= (const float*)d_in[10];
    float* out = (float*)d_out;

    float* wsf      = (float*)d_ws;
    float* dbl      = wsf;                                //   393,216 f
    float* dbl_part = dbl      + (size_t)393216;          // 1,572,864 f
    float* dtb      = dbl_part + (size_t)1572864;         // 8,388,608 f
    float* sum_a    = dtb      + (size_t)8388608;         // 2,097,152 f
    float* sum_h    = sum_a    + (size_t)2097152;         // 2,097,152 f
    unsigned short* xz_bf    = (unsigned short*)(sum_h + 2097152); // 16,777,216 us
    unsigned short* xconv_bf = xz_bf    + (size_t)16777216;        //  8,388,608 us
    unsigned short* hnorm_bf = xconv_bf + (size_t)8388608;         //  4,194,304 us
    unsigned short* ybuf_bf  = hnorm_bf + (size_t)4194304;         //  8,388,608 us
    unsigned short* wi_bf    = ybuf_bf  + (size_t)8388608;         //  4,194,304 us
    unsigned short* wo_bf    = wi_bf    + (size_t)4194304;         //  2,097,152 us
    unsigned short* wx_bf    = wo_bf    + (size_t)2097152;         //    262,144 us (128-row pad)
    unsigned short* wdt_bf   = wx_bf    + (size_t)262144;          //    131,072 us
    unsigned short* dtr_bf   = wdt_bf   + (size_t)131072;          //    262,144 us

    // fused weight casts
    {
        int n0 = 2 * D_INNER * D_MODEL / 4;   // wi
        int n1 = D_MODEL * D_INNER / 4;       // wo
        int n2 = DBL_N * D_INNER / 4;         // wx
        int n3 = D_INNER * DT_RANK / 4;       // wdt
        int tot = n0 + n1 + n2 + n3;
        cast4_kernel<<<(tot + 255) / 256, 256, 0, stream>>>(
            (const float4*)in_proj_w,  (ushort4*)wi_bf,  n0,
            (const float4*)out_proj_w, (ushort4*)wo_bf,  n1,
            (const float4*)x_proj_w,   (ushort4*)wx_bf,  n2,
            (const float4*)dt_proj_w,  (ushort4*)wdt_bf, n3);
    }

    // 1. RMSNorm -> bf16
    rmsnorm_kernel<<<NTOK, 256, 0, stream>>>(hs, norm_w, hnorm_bf);
    // 2. in_proj (MFMA): xz_bf = hnorm @ in_proj_w^T  (bf16 out, packed stores)
    mfma_gemm_kernel<<<dim3((2 * D_INNER) / 128, NTOK / 128), 256, 0, stream>>>(
        hnorm_bf, D_MODEL, wi_bf, D_MODEL, nullptr, 0, xz_bf, 2 * D_INNER,
        D_MODEL, 2 * D_INNER, nullptr, 0, 0);
    // 3. depthwise causal conv + SiLU (bf16 in/out)
    conv_silu_kernel<<<(NTOK * D_INNER) / 256, 256, 0, stream>>>(
        xz_bf, conv_w, conv_b, xconv_bf);
    // 4. x_proj (MFMA, split-K x4): dbl_part[seg] = xconv @ x_proj_w^T (N=96)
    mfma_gemm_kernel<<<dim3(1, NTOK / 128, 4), 256, 0, stream>>>(
        xconv_bf, D_INNER, wx_bf, D_INNER, dbl_part, DBL_N, nullptr, 0,
        D_INNER / 4, DBL_N, nullptr, 0, (size_t)NTOK * DBL_N);
    reduce_xproj_kernel<<<(NTOK * DBL_N + 255) / 256, 256, 0, stream>>>(
        dbl_part, dbl, dtr_bf);
    // 5. dt_proj: dedicated 64x64-tile kernel (2048 blocks), bias + fast softplus
    dtproj_kernel<<<dim3(D_INNER / 64, NTOK / 64), 256, 0, stream>>>(
        dtr_bf, wdt_bf, dt_proj_b, dtb);
    // 6. scan: phase1 -> carry -> phase3
    scan_phase1_kernel<<<dim3(NCHUNK, D_INNER / 256, B_SZ), 256, 0, stream>>>(
        dtb, xconv_bf, dbl, A_log, sum_a, sum_h);
    scan_carry_kernel<<<(B_SZ * D_INNER * D_STATE) / 256, 256, 0, stream>>>(sum_a, sum_h);
    scan_phase3_kernel<<<dim3(NCHUNK, D_INNER / 256, B_SZ), 256, 0, stream>>>(
        dtb, xconv_bf, xz_bf, dbl, A_log, Dvec, sum_h, ybuf_bf);
    // 7. out_proj (MFMA) + residual -> d_out (float4 stores + float4 residual loads)
    mfma_gemm_kernel<<<dim3(D_MODEL / 128, NTOK / 128), 256, 0, stream>>>(
        ybuf_bf, D_INNER, wo_bf, D_INNER, out, D_MODEL, nullptr, 0,
        D_INNER, D_MODEL, hs, D_MODEL, 0);
}